// Round 1
// baseline (1199.859 us; speedup 1.0000x reference)
//
#include <hip/hip_runtime.h>
#include <cstdint>

// Problem constants
// z: [16, 256, 32, 32] f32, codebook: [8192, 256] f32
// outputs: z_q_out [16,256,32,32] f32 | index [16,32,32] (as f32) | loss | diversity
#define NPOS    16384      // 16*32*32 positions
#define DIM     256
#define NCODES  8192
#define ZSTRIDE 262144     // 256*1024 floats per batch in z
#define NELEM   4194304    // 16*256*32*32

// ws layout (bytes)
#define WS_IDX_OFF   0        // int[16384]
#define WS_E2_OFF    65536    // float[8192]
#define WS_PRES_OFF  98304    // uint32[16*256] = 16KB
#define WS_PART_OFF  114688   // float[256]

// ---------------------------------------------------------------------------
// Kernel 1: e2[n] = sum_k cb[n][k]^2.  One wave per row, float4 loads.
// ---------------------------------------------------------------------------
__global__ __launch_bounds__(256)
void e2_kernel(const float* __restrict__ cb, float* __restrict__ e2) {
    const int row  = blockIdx.x * 4 + (threadIdx.x >> 6);
    const int lane = threadIdx.x & 63;
    const float4 v = *(const float4*)(cb + (size_t)row * DIM + lane * 4);
    float s = v.x * v.x + v.y * v.y + v.z * v.z + v.w * v.w;
#pragma unroll
    for (int o = 32; o > 0; o >>= 1) s += __shfl_xor(s, o);
    if (lane == 0) e2[row] = s;
}

// ---------------------------------------------------------------------------
// Kernel 2: fused distance-GEMM + argmin.
// Block = 512 threads, BM=64 positions (full K=256 of z staged in LDS once),
// loop code tiles of BN=256, K chunks of 16.  Thread tile 4 pos x 8 codes.
// Thread tx owns codes {4tx..4tx+3} and {128+4tx..} so LDS b128 reads are
// contiguous across the 32-lane group (conflict-free).
// ---------------------------------------------------------------------------
__global__ __launch_bounds__(512, 1)
void argmin_kernel(const float* __restrict__ z, const float* __restrict__ cb,
                   const float* __restrict__ e2, float* __restrict__ out_idxf,
                   int* __restrict__ ws_idx, unsigned int* __restrict__ presence) {
    __shared__ float zt[256][64];   // [k][m]   64 KB
    __shared__ float et[16][256];   // [k][n]   16 KB
    __shared__ float e2t[256];

    const int tile = blockIdx.x;          // 0..255 (one per 64-position tile)
    const int b    = tile >> 4;           // 16 tiles per batch image
    const int hw0  = (tile & 15) * 64;
    const int tid  = threadIdx.x;

    {   // stage z tile: zt[c][m] = z[b][c][hw0+m]; coalesced over m
        const float* zb = z + (size_t)b * ZSTRIDE + hw0;
        const int m  = tid & 63;
        const int c0 = tid >> 6;          // 0..7
#pragma unroll
        for (int c = 0; c < 256; c += 8)
            zt[c + c0][m] = zb[(size_t)(c + c0) * 1024 + m];
    }

    const int tx  = tid & 31;             // code group
    const int ty  = tid >> 5;             // position group (0..15)
    const int tx4 = tx * 4;
    const int ty4 = ty * 4;

    float minv[4] = {1e30f, 1e30f, 1e30f, 1e30f};
    int   mina[4] = {0, 0, 0, 0};

    for (int n0 = 0; n0 < NCODES; n0 += 256) {
        __syncthreads();                  // prev epilogue done before e2t overwrite
        if (tid < 256) e2t[tid] = e2[n0 + tid];

        float acc[4][8];
#pragma unroll
        for (int i = 0; i < 4; ++i)
#pragma unroll
            for (int j = 0; j < 8; ++j) acc[i][j] = 0.0f;

        for (int k0 = 0; k0 < 256; k0 += 16) {
            __syncthreads();              // prev chunk's reads of et done
            {   // stage et chunk: 256 codes x 16 k, transposed
                const int n  = tid >> 2;          // 0..127
                const int kq = (tid & 3) * 4;     // 0,4,8,12
                const float4 v0 = *(const float4*)(cb + (size_t)(n0 + n)       * DIM + k0 + kq);
                const float4 v1 = *(const float4*)(cb + (size_t)(n0 + n + 128) * DIM + k0 + kq);
                et[kq + 0][n] = v0.x; et[kq + 1][n] = v0.y;
                et[kq + 2][n] = v0.z; et[kq + 3][n] = v0.w;
                et[kq + 0][n + 128] = v1.x; et[kq + 1][n + 128] = v1.y;
                et[kq + 2][n + 128] = v1.z; et[kq + 3][n + 128] = v1.w;
            }
            __syncthreads();
#pragma unroll
            for (int k = 0; k < 16; ++k) {
                const float4 av = *(const float4*)(&zt[k0 + k][ty4]);
                const float4 b0 = *(const float4*)(&et[k][tx4]);
                const float4 b1 = *(const float4*)(&et[k][tx4 + 128]);
                const float a_[4] = {av.x, av.y, av.z, av.w};
                const float b_[8] = {b0.x, b0.y, b0.z, b0.w, b1.x, b1.y, b1.z, b1.w};
#pragma unroll
                for (int i = 0; i < 4; ++i)
#pragma unroll
                    for (int j = 0; j < 8; ++j)
                        acc[i][j] = fmaf(a_[i], b_[j], acc[i][j]);
            }
        }

        // epilogue: d = e2 - 2*dot; running argmin (ascending code order kept)
        const float4 e2a = *(const float4*)(&e2t[tx4]);
        const float4 e2b = *(const float4*)(&e2t[tx4 + 128]);
        const float ev[8] = {e2a.x, e2a.y, e2a.z, e2a.w, e2b.x, e2b.y, e2b.z, e2b.w};
#pragma unroll
        for (int i = 0; i < 4; ++i) {
#pragma unroll
            for (int j = 0; j < 8; ++j) {
                const float d = ev[j] - 2.0f * acc[i][j];
                const int   n = n0 + ((j < 4) ? (tx4 + j) : (128 + tx4 + (j - 4)));
                if (d < minv[i]) { minv[i] = d; mina[i] = n; }
            }
        }
    }

    // cross-lane argmin across the 32 tx-lanes sharing each position
#pragma unroll
    for (int i = 0; i < 4; ++i) {
        float v = minv[i];
        int   a = mina[i];
#pragma unroll
        for (int o = 16; o > 0; o >>= 1) {
            const float ov = __shfl_xor(v, o);
            const int   oa = __shfl_xor(a, o);
            if (ov < v || (ov == v && oa < a)) { v = ov; a = oa; }
        }
        if (tx == 0) {
            const int gp = tile * 64 + ty4 + i;   // = b*1024 + hw0 + (ty4+i)
            ws_idx[gp]   = a;
            out_idxf[gp] = (float)a;
            atomicOr(&presence[b * 256 + (a >> 5)], 1u << (a & 31));
        }
    }
}

// ---------------------------------------------------------------------------
// Kernel 3: gather z_q, straight-through output (channel-first), loss partials.
// One block per 64-position tile; lanes = positions (coalesced z/out access);
// codebook rows gathered via L1/L2.
// ---------------------------------------------------------------------------
__global__ __launch_bounds__(256)
void output_kernel(const float* __restrict__ z, const float* __restrict__ cb,
                   const int* __restrict__ ws_idx, float* __restrict__ out,
                   float* __restrict__ partial) {
    __shared__ float red[256];
    const int tile = blockIdx.x;
    const int b    = tile >> 4;
    const int hw0  = (tile & 15) * 64;
    const int tid  = threadIdx.x;
    const int m    = tid & 63;
    const int cg   = tid >> 6;            // 0..3 (channel quarter)

    const int gp   = tile * 64 + m;
    const int code = ws_idx[gp];
    const float* crow = cb  + (size_t)code * DIM;
    const float* zb   = z   + (size_t)b * ZSTRIDE + hw0 + m;
    float*       ob   = out + (size_t)b * ZSTRIDE + hw0 + m;

    float lsum = 0.0f;
#pragma unroll
    for (int q = 0; q < 16; ++q) {
        const int c = (cg * 16 + q) * 4;
        const float4 e = *(const float4*)(crow + c);
        const float z0 = zb[(size_t)(c + 0) * 1024];
        const float z1 = zb[(size_t)(c + 1) * 1024];
        const float z2 = zb[(size_t)(c + 2) * 1024];
        const float z3 = zb[(size_t)(c + 3) * 1024];
        const float d0 = e.x - z0, d1 = e.y - z1, d2 = e.z - z2, d3 = e.w - z3;
        lsum += d0 * d0 + d1 * d1 + d2 * d2 + d3 * d3;
        // straight-through: zl + (z_q - zl), same expression as reference
        ob[(size_t)(c + 0) * 1024] = z0 + d0;
        ob[(size_t)(c + 1) * 1024] = z1 + d1;
        ob[(size_t)(c + 2) * 1024] = z2 + d2;
        ob[(size_t)(c + 3) * 1024] = z3 + d3;
    }
    red[tid] = lsum;
    __syncthreads();
    for (int o = 128; o > 0; o >>= 1) {
        if (tid < o) red[tid] += red[tid + o];
        __syncthreads();
    }
    if (tid == 0) partial[tile] = red[0];
}

// ---------------------------------------------------------------------------
// Kernel 4: finalize loss + diversity scalars (deterministic tree reduce).
// ---------------------------------------------------------------------------
__global__ __launch_bounds__(256)
void finalize_kernel(const float* __restrict__ partial,
                     const unsigned int* __restrict__ presence,
                     float* __restrict__ out_loss, float* __restrict__ out_div) {
    __shared__ float sred[256];
    __shared__ int   ired[256];
    const int tid = threadIdx.x;
    float s = partial[tid];
    int cnt = 0;
    for (int w = tid; w < 16 * 256; w += 256) cnt += __popc(presence[w]);
    sred[tid] = s;
    ired[tid] = cnt;
    __syncthreads();
    for (int o = 128; o > 0; o >>= 1) {
        if (tid < o) { sred[tid] += sred[tid + o]; ired[tid] += ired[tid + o]; }
        __syncthreads();
    }
    if (tid == 0) {
        // loss = mean(diff^2) + 0.25*mean(diff^2)
        out_loss[0] = 1.25f * sred[0] / (float)NELEM;
        out_div[0]  = (float)ired[0] / (float)NPOS;
    }
}

// ---------------------------------------------------------------------------
extern "C" void kernel_launch(void* const* d_in, const int* in_sizes, int n_in,
                              void* d_out, int out_size, void* d_ws, size_t ws_size,
                              hipStream_t stream) {
    const float* z  = (const float*)d_in[0];
    const float* cb = (const float*)d_in[1];
    float* out = (float*)d_out;
    char*  ws  = (char*)d_ws;

    int*          ws_idx   = (int*)(ws + WS_IDX_OFF);
    float*        e2       = (float*)(ws + WS_E2_OFF);
    unsigned int* presence = (unsigned int*)(ws + WS_PRES_OFF);
    float*        partial  = (float*)(ws + WS_PART_OFF);

    float* out_zq   = out;                    // [16,256,32,32]
    float* out_idxf = out + NELEM;            // [16,32,32] as float
    float* out_loss = out + NELEM + NPOS;     // scalar
    float* out_div  = out + NELEM + NPOS + 1; // scalar

    // zero presence bitmap (atomicOr target); partials are fully overwritten
    hipMemsetAsync(ws + WS_PRES_OFF, 0, 16 * 256 * sizeof(unsigned int), stream);

    e2_kernel<<<NCODES / 4, 256, 0, stream>>>(cb, e2);
    argmin_kernel<<<NPOS / 64, 512, 0, stream>>>(z, cb, e2, out_idxf, ws_idx, presence);
    output_kernel<<<NPOS / 64, 256, 0, stream>>>(z, cb, ws_idx, out_zq, partial);
    finalize_kernel<<<1, 256, 0, stream>>>(partial, presence, out_loss, out_div);
}

// Round 2
// 627.066 us; speedup vs baseline: 1.9134x; 1.9134x over previous
//
#include <hip/hip_runtime.h>
#include <cstdint>

typedef unsigned short u16;
typedef unsigned int   u32;
typedef __attribute__((ext_vector_type(8))) short bf16x8;
typedef __attribute__((ext_vector_type(4))) float f32x4;

// Problem constants
#define NPOS    16384
#define DIM     256
#define NCODES  8192
#define ZSTRIDE 262144     // 256*1024 floats per batch image
#define NELEM   4194304
#define TAU     6e-3f

// ws layout (bytes), total ~38 MB
#define WS_AHI   0u            // u16[16384*256] tiled [128 mt][8 kt][128][32]
#define WS_ALO   8388608u
#define WS_BHI   16777216u     // u16[8192*256]  tiled [64 nt][8 kt][128][32]
#define WS_BLO   20971520u
#define WS_E2    25165824u     // f32[8192]
#define WS_WV1   25198592u     // f32[64][16384]
#define WS_WI1   29392896u     // i32[64][16384]
#define WS_WV2   33587200u     // f32[64][16384]
#define WS_IDX   37781504u     // i32[16384]
#define WS_PRES  37847040u     // u32[16*256]
#define WS_RCNT  37863424u     // i32[1] (+pad)
#define WS_RLIST 37863680u     // i32[16384]
#define WS_PART  37929216u     // f32[256]

__device__ __forceinline__ u16 f2bf(float x) {   // round-to-nearest-even bf16
    u32 u = __float_as_uint(x);
    return (u16)((u + 0x7FFFu + ((u >> 16) & 1u)) >> 16);
}
__device__ __forceinline__ float bf2f(u16 h) { return __uint_as_float((u32)h << 16); }

__device__ __forceinline__ void gload_lds16(const void* g, void* l) {
    __builtin_amdgcn_global_load_lds(
        (const __attribute__((address_space(1))) void*)g,
        (__attribute__((address_space(3))) void*)l, 16, 0, 0);
}

__device__ __forceinline__ void top2_push(float& v1, int& i1, float& v2, float d, int c) {
    bool better = (d < v1) || (d == v1 && c < i1);
    v2 = fminf(v2, better ? v1 : d);
    if (better) { v1 = d; i1 = c; }
}
__device__ __forceinline__ void top2_merge(float& v1, int& i1, float& v2,
                                           float ov1, int oi1, float ov2) {
    bool better = (ov1 < v1) || (ov1 == v1 && oi1 < i1);
    float vb = better ? v1 : ov1;
    v2 = fminf(fminf(v2, ov2), vb);
    if (better) { v1 = ov1; i1 = oi1; }
}

// ---------------------------------------------------------------------------
// pre_cb: codebook [8192][256] f32 -> Bhi/Blo tiled [nt][kt][128][32] bf16 + e2.
// One wave per row; lane covers 4 k.
// ---------------------------------------------------------------------------
__global__ __launch_bounds__(256)
void pre_cb(const float* __restrict__ cb, u16* __restrict__ Bhi, u16* __restrict__ Blo,
            float* __restrict__ e2) {
    const int row  = blockIdx.x * 4 + (threadIdx.x >> 6);
    const int lane = threadIdx.x & 63;
    const float4 v = *(const float4*)(cb + (size_t)row * DIM + lane * 4);
    float s = v.x * v.x + v.y * v.y + v.z * v.z + v.w * v.w;
#pragma unroll
    for (int o = 32; o > 0; o >>= 1) s += __shfl_xor(s, o);
    if (lane == 0) e2[row] = s;

    const float vv[4] = {v.x, v.y, v.z, v.w};
    u16 h[4], l[4];
#pragma unroll
    for (int j = 0; j < 4; ++j) { h[j] = f2bf(vv[j]); l[j] = f2bf(vv[j] - bf2f(h[j])); }

    const int nt = row >> 7, pr = row & 127, kt = lane >> 3, kk = (lane & 7) * 4;
    const size_t dst = ((size_t)(nt * 8 + kt) * 128 + pr) * 32 + kk;
    *(uint2*)(Bhi + dst) = make_uint2((u32)h[0] | ((u32)h[1] << 16), (u32)h[2] | ((u32)h[3] << 16));
    *(uint2*)(Blo + dst) = make_uint2((u32)l[0] | ((u32)l[1] << 16), (u32)l[2] | ((u32)l[3] << 16));
}

// ---------------------------------------------------------------------------
// pre_z: z [16][256][1024] f32 (channel-major) -> Ahi/Alo tiled [mt][kt][128][32].
// LDS transpose so both reads and writes are coalesced.
// ---------------------------------------------------------------------------
__global__ __launch_bounds__(256)
void pre_z(const float* __restrict__ z, u16* __restrict__ Ahi, u16* __restrict__ Alo) {
    __shared__ u16 his[128 * 34], los[128 * 34];
    const int m = blockIdx.x;                 // 0..127 m-tile
    const int b = m >> 3, hw0 = (m & 7) * 128;
    const int t = threadIdx.x;
    const int p = t & 127, ch = t >> 7;       // position, channel parity

    for (int kt = 0; kt < 8; ++kt) {
        __syncthreads();                      // protect LDS from prev flush readers
#pragma unroll
        for (int sub = 0; sub < 16; ++sub) {
            const int cl = sub * 2 + ch;
            const float v = z[(size_t)b * ZSTRIDE + (size_t)(kt * 32 + cl) * 1024 + hw0 + p];
            const u16 h = f2bf(v);
            his[p * 34 + cl] = h;
            los[p * 34 + cl] = f2bf(v - bf2f(h));
        }
        __syncthreads();
        // flush: thread -> (p2 = t>>1, half = (t&1)*16), contiguous 32B stores
        const int p2 = t >> 1, half = (t & 1) * 16;
        const size_t dst = ((size_t)(m * 8 + kt) * 128 + p2) * 32 + half;
        u32 wh[8], wl[8];
#pragma unroll
        for (int j = 0; j < 8; ++j) {
            wh[j] = (u32)his[p2 * 34 + half + 2 * j] | ((u32)his[p2 * 34 + half + 2 * j + 1] << 16);
            wl[j] = (u32)los[p2 * 34 + half + 2 * j] | ((u32)los[p2 * 34 + half + 2 * j + 1] << 16);
        }
        *(uint4*)(Ahi + dst)     = make_uint4(wh[0], wh[1], wh[2], wh[3]);
        *(uint4*)(Ahi + dst + 8) = make_uint4(wh[4], wh[5], wh[6], wh[7]);
        *(uint4*)(Alo + dst)     = make_uint4(wl[0], wl[1], wl[2], wl[3]);
        *(uint4*)(Alo + dst + 8) = make_uint4(wl[4], wl[5], wl[6], wl[7]);
    }
}

// ---------------------------------------------------------------------------
// gemm_argmin: K=768 bf16 GEMM (z_hi.cb_hi + z_hi.cb_lo + z_lo.cb_hi), m97
// structure: 128x128 tile, 4 waves 2x2, BK=32, global_load_lds w16, 16x16x32
// MFMA. Epilogue: per-position top-2 over this tile's 128 codes -> ws.
// ---------------------------------------------------------------------------
__global__ __launch_bounds__(256)
void gemm_argmin(const u16* __restrict__ Ahi, const u16* __restrict__ Alo,
                 const u16* __restrict__ Bhi, const u16* __restrict__ Blo,
                 const float* __restrict__ e2,
                 float* __restrict__ wv1, int* __restrict__ wi1, float* __restrict__ wv2) {
    __shared__ u16 As[4096], Bs[4096];        // 128x32 each
    __shared__ float lv1[256]; __shared__ int li1[256]; __shared__ float lv2[256];

    // XCD swizzle: each XCD owns 8 consecutive B-panels; 128-block runs share one
    int wg = (blockIdx.x & 7) * 1024 + (blockIdx.x >> 3);
    const int nt = wg / 128, mt = wg % 128;

    const int tid = threadIdx.x;
    const int wv  = tid >> 6, lane = tid & 63;
    const int wr  = wv >> 1, wc = wv & 1;
    const int l15 = lane & 15, lq = lane >> 4;
    const int woff = (tid & 192) * 16;        // wave-uniform LDS byte base

    const int cbase = nt * 128 + wc * 64 + l15;
    float e2v[4];
#pragma unroll
    for (int ni = 0; ni < 4; ++ni) e2v[ni] = e2[cbase + ni * 16];

    f32x4 acc[4][4] = {};
    const size_t atile = (size_t)mt * 8 * 4096, btile = (size_t)nt * 8 * 4096;

    for (int ks = 0; ks < 24; ++ks) {
        const int ph = ks >> 3, kt = ks & 7;
        const u16* Ap = (ph < 2 ? Ahi : Alo) + atile + (size_t)kt * 4096;
        const u16* Bp = (ph == 1 ? Blo : Bhi) + btile + (size_t)kt * 4096;
        gload_lds16(Ap + tid * 8,        (char*)As + woff);
        gload_lds16(Ap + 2048 + tid * 8, (char*)As + 4096 + woff);
        gload_lds16(Bp + tid * 8,        (char*)Bs + woff);
        gload_lds16(Bp + 2048 + tid * 8, (char*)Bs + 4096 + woff);
        __syncthreads();                      // drains vmcnt -> LDS tiles ready

        bf16x8 af[4], bfr[4];
#pragma unroll
        for (int i = 0; i < 4; ++i) {
            af[i]  = *(const bf16x8*)(As + (wr * 64 + i * 16 + l15) * 32 + lq * 8);
            bfr[i] = *(const bf16x8*)(Bs + (wc * 64 + i * 16 + l15) * 32 + lq * 8);
        }
#pragma unroll
        for (int i = 0; i < 4; ++i)
#pragma unroll
            for (int j = 0; j < 4; ++j)
                acc[i][j] = __builtin_amdgcn_mfma_f32_16x16x32_bf16(af[i], bfr[j], acc[i][j], 0, 0, 0);
        __syncthreads();                      // all reads done before next stage
    }

    // epilogue: d = e2 - 2S; per-row top-2 over wave's 64 cols; C/D layout:
    // col = lane&15, row = (lane>>4)*4 + reg  (m89/m91 verified)
#pragma unroll
    for (int mi = 0; mi < 4; ++mi) {
#pragma unroll
        for (int j = 0; j < 4; ++j) {
            float v1 = 3e38f, v2 = 3e38f; int i1 = 0x7fffffff;
#pragma unroll
            for (int ni = 0; ni < 4; ++ni) {
                const float d = fmaf(-2.0f, acc[mi][ni][j], e2v[ni]);
                top2_push(v1, i1, v2, d, cbase + ni * 16);
            }
#pragma unroll
            for (int off = 1; off <= 8; off <<= 1) {
                const float ov1 = __shfl_xor(v1, off);
                const int   oi1 = __shfl_xor(i1, off);
                const float ov2 = __shfl_xor(v2, off);
                top2_merge(v1, i1, v2, ov1, oi1, ov2);
            }
            if (l15 == 0) {
                const int row = wr * 64 + mi * 16 + lq * 4 + j;
                lv1[row * 2 + wc] = v1; li1[row * 2 + wc] = i1; lv2[row * 2 + wc] = v2;
            }
        }
    }
    __syncthreads();
    if (tid < 128) {
        float v1 = lv1[tid * 2], v2 = lv2[tid * 2]; int i1 = li1[tid * 2];
        top2_merge(v1, i1, v2, lv1[tid * 2 + 1], li1[tid * 2 + 1], lv2[tid * 2 + 1]);
        const size_t o = (size_t)nt * NPOS + (size_t)mt * 128 + tid;
        wv1[o] = v1; wi1[o] = i1; wv2[o] = v2;
    }
}

// ---------------------------------------------------------------------------
// merge: reduce 64 tiles' top-2 per position; margin test -> rescue list.
// ---------------------------------------------------------------------------
__global__ __launch_bounds__(256)
void merge_kernel(const float* __restrict__ wv1, const int* __restrict__ wi1,
                  const float* __restrict__ wv2, int* __restrict__ ws_idx,
                  float* __restrict__ out_idxf, unsigned int* __restrict__ presence,
                  int* __restrict__ rcnt, int* __restrict__ rlist) {
    const int pos = blockIdx.x * 256 + threadIdx.x;
    float v1 = 3e38f, v2 = 3e38f; int i1 = 0x7fffffff;
    for (int nt = 0; nt < 64; ++nt) {
        const size_t o = (size_t)nt * NPOS + pos;
        top2_merge(v1, i1, v2, wv1[o], wi1[o], wv2[o]);
    }
    ws_idx[pos]   = i1;
    out_idxf[pos] = (float)i1;
    if (v2 - v1 < TAU) {
        const int s = atomicAdd(rcnt, 1);
        rlist[s] = pos;
    } else {
        atomicOr(&presence[(pos >> 10) * 256 + (i1 >> 5)], 1u << (i1 & 31));
    }
}

// ---------------------------------------------------------------------------
// rescue: exact fp32 full scan for flagged positions (expected ~10).
// ---------------------------------------------------------------------------
__global__ __launch_bounds__(256)
void rescue_kernel(const float* __restrict__ z, const float* __restrict__ cb,
                   const float* __restrict__ e2, const int* __restrict__ rcnt,
                   const int* __restrict__ rlist, int* __restrict__ ws_idx,
                   float* __restrict__ out_idxf, unsigned int* __restrict__ presence) {
    __shared__ float zvec[256];
    __shared__ float rv[256]; __shared__ int ri[256];
    const int n = rcnt[0];
    const int t = threadIdx.x;
    for (int e = blockIdx.x; e < n; e += gridDim.x) {
        const int pos = rlist[e];
        const int b = pos >> 10, hw = pos & 1023;
        __syncthreads();
        zvec[t] = z[(size_t)b * ZSTRIDE + (size_t)t * 1024 + hw];
        __syncthreads();
        float bv = 3e38f; int bi = 0x7fffffff;
        for (int c = t; c < NCODES; c += 256) {
            const float* cr = cb + (size_t)c * DIM;
            float dot = 0.f;
            for (int k = 0; k < DIM; k += 4) {
                const float4 cv = *(const float4*)(cr + k);
                dot = fmaf(zvec[k], cv.x, dot);
                dot = fmaf(zvec[k + 1], cv.y, dot);
                dot = fmaf(zvec[k + 2], cv.z, dot);
                dot = fmaf(zvec[k + 3], cv.w, dot);
            }
            const float d = fmaf(-2.f, dot, e2[c]);
            if (d < bv) { bv = d; bi = c; }   // ascending c: strict < keeps smallest
        }
        rv[t] = bv; ri[t] = bi;
        __syncthreads();
        for (int o = 128; o > 0; o >>= 1) {
            if (t < o) {
                const float ov = rv[t + o]; const int oi = ri[t + o];
                if (ov < rv[t] || (ov == rv[t] && oi < ri[t])) { rv[t] = ov; ri[t] = oi; }
            }
            __syncthreads();
        }
        if (t == 0) {
            ws_idx[pos] = ri[0]; out_idxf[pos] = (float)ri[0];
            atomicOr(&presence[b * 256 + (ri[0] >> 5)], 1u << (ri[0] & 31));
        }
    }
}

// ---------------------------------------------------------------------------
// output: gather z_q, straight-through channel-first output, loss partials.
// ---------------------------------------------------------------------------
__global__ __launch_bounds__(256)
void output_kernel(const float* __restrict__ z, const float* __restrict__ cb,
                   const int* __restrict__ ws_idx, float* __restrict__ out,
                   float* __restrict__ partial) {
    __shared__ float red[256];
    const int tile = blockIdx.x;
    const int b    = tile >> 4;
    const int hw0  = (tile & 15) * 64;
    const int tid  = threadIdx.x;
    const int m    = tid & 63;
    const int cg   = tid >> 6;

    const int gp   = tile * 64 + m;
    const int code = ws_idx[gp];
    const float* crow = cb  + (size_t)code * DIM;
    const float* zb   = z   + (size_t)b * ZSTRIDE + hw0 + m;
    float*       ob   = out + (size_t)b * ZSTRIDE + hw0 + m;

    float lsum = 0.0f;
#pragma unroll
    for (int q = 0; q < 16; ++q) {
        const int c = (cg * 16 + q) * 4;
        const float4 e = *(const float4*)(crow + c);
        const float z0 = zb[(size_t)(c + 0) * 1024];
        const float z1 = zb[(size_t)(c + 1) * 1024];
        const float z2 = zb[(size_t)(c + 2) * 1024];
        const float z3 = zb[(size_t)(c + 3) * 1024];
        const float d0 = e.x - z0, d1 = e.y - z1, d2 = e.z - z2, d3 = e.w - z3;
        lsum += d0 * d0 + d1 * d1 + d2 * d2 + d3 * d3;
        ob[(size_t)(c + 0) * 1024] = z0 + d0;
        ob[(size_t)(c + 1) * 1024] = z1 + d1;
        ob[(size_t)(c + 2) * 1024] = z2 + d2;
        ob[(size_t)(c + 3) * 1024] = z3 + d3;
    }
    red[tid] = lsum;
    __syncthreads();
    for (int o = 128; o > 0; o >>= 1) {
        if (tid < o) red[tid] += red[tid + o];
        __syncthreads();
    }
    if (tid == 0) partial[tile] = red[0];
}

__global__ __launch_bounds__(256)
void finalize_kernel(const float* __restrict__ partial,
                     const unsigned int* __restrict__ presence,
                     float* __restrict__ out_loss, float* __restrict__ out_div) {
    __shared__ float sred[256];
    __shared__ int   ired[256];
    const int tid = threadIdx.x;
    float s = partial[tid];
    int cnt = 0;
    for (int w = tid; w < 16 * 256; w += 256) cnt += __popc(presence[w]);
    sred[tid] = s; ired[tid] = cnt;
    __syncthreads();
    for (int o = 128; o > 0; o >>= 1) {
        if (tid < o) { sred[tid] += sred[tid + o]; ired[tid] += ired[tid + o]; }
        __syncthreads();
    }
    if (tid == 0) {
        out_loss[0] = 1.25f * sred[0] / (float)NELEM;
        out_div[0]  = (float)ired[0] / (float)NPOS;
    }
}

// ---------------------------------------------------------------------------
extern "C" void kernel_launch(void* const* d_in, const int* in_sizes, int n_in,
                              void* d_out, int out_size, void* d_ws, size_t ws_size,
                              hipStream_t stream) {
    const float* z  = (const float*)d_in[0];
    const float* cb = (const float*)d_in[1];
    float* out = (float*)d_out;
    char*  ws  = (char*)d_ws;

    u16*   Ahi = (u16*)(ws + WS_AHI);
    u16*   Alo = (u16*)(ws + WS_ALO);
    u16*   Bhi = (u16*)(ws + WS_BHI);
    u16*   Blo = (u16*)(ws + WS_BLO);
    float* e2  = (float*)(ws + WS_E2);
    float* wv1 = (float*)(ws + WS_WV1);
    int*   wi1 = (int*)(ws + WS_WI1);
    float* wv2 = (float*)(ws + WS_WV2);
    int*   ws_idx = (int*)(ws + WS_IDX);
    unsigned int* presence = (unsigned int*)(ws + WS_PRES);
    int*   rcnt  = (int*)(ws + WS_RCNT);
    int*   rlist = (int*)(ws + WS_RLIST);
    float* partial = (float*)(ws + WS_PART);

    float* out_zq   = out;
    float* out_idxf = out + NELEM;
    float* out_loss = out + NELEM + NPOS;
    float* out_div  = out + NELEM + NPOS + 1;

    hipMemsetAsync(ws + WS_PRES, 0, 16 * 256 * sizeof(unsigned int), stream);
    hipMemsetAsync(ws + WS_RCNT, 0, sizeof(int), stream);

    pre_cb<<<NCODES / 4, 256, 0, stream>>>(cb, Bhi, Blo, e2);
    pre_z<<<128, 256, 0, stream>>>(z, Ahi, Alo);
    gemm_argmin<<<8192, 256, 0, stream>>>(Ahi, Alo, Bhi, Blo, e2, wv1, wi1, wv2);
    merge_kernel<<<NPOS / 256, 256, 0, stream>>>(wv1, wi1, wv2, ws_idx, out_idxf,
                                                 presence, rcnt, rlist);
    rescue_kernel<<<64, 256, 0, stream>>>(z, cb, e2, rcnt, rlist, ws_idx, out_idxf, presence);
    output_kernel<<<NPOS / 64, 256, 0, stream>>>(z, cb, ws_idx, out_zq, partial);
    finalize_kernel<<<1, 256, 0, stream>>>(partial, presence, out_loss, out_div);
}

// Round 3
// 551.190 us; speedup vs baseline: 2.1769x; 1.1377x over previous
//
#include <hip/hip_runtime.h>
#include <cstdint>

typedef unsigned short u16;
typedef unsigned int   u32;
typedef __attribute__((ext_vector_type(8))) short bf16x8;
typedef __attribute__((ext_vector_type(4))) float f32x4;

// Problem constants
#define NPOS    16384
#define DIM     256
#define NCODES  8192
#define ZSTRIDE 262144     // 256*1024 floats per batch image
#define NELEM   4194304
#define TAU     6e-3f

// ws layout (bytes), total ~27 MB
#define WS_AHI    0u           // u16[16384*256] tiled [128 mt][8 kt][128][32]
#define WS_ALO    8388608u
#define WS_BHI    16777216u    // u16[8192*256]  tiled [64 nt][8 kt][128][32]
#define WS_BLO    20971520u
#define WS_E2     25165824u    // f32[8192]
#define WS_WV1    25198592u    // f32[8][16384]
#define WS_WI1    25722880u    // i32[8][16384]
#define WS_WV2    26247168u    // f32[8][16384]
#define WS_IDX    26771456u    // i32[16384]
#define WS_PRES   26836992u    // u32[16*256]
#define WS_RCNT   26853376u    // i32
#define WS_LDEL   26853380u    // f32 loss delta
#define WS_RLIST  26853632u    // i32[16384]
#define WS_PART   26919168u    // f32[256]

__device__ __forceinline__ u16 f2bf(float x) {   // round-to-nearest-even bf16
    u32 u = __float_as_uint(x);
    return (u16)((u + 0x7FFFu + ((u >> 16) & 1u)) >> 16);
}
__device__ __forceinline__ float bf2f(u16 h) { return __uint_as_float((u32)h << 16); }

__device__ __forceinline__ void gload_lds16(const void* g, void* l) {
    __builtin_amdgcn_global_load_lds(
        (const __attribute__((address_space(1))) void*)g,
        (__attribute__((address_space(3))) void*)l, 16, 0, 0);
}

// top-2 without index tie-break: an exact tie leaves v2 == v1 -> margin 0 -> rescued
__device__ __forceinline__ void top2_push(float& v1, int& i1, float& v2, float d, int c) {
    const bool better = d < v1;
    v2 = fminf(v2, better ? v1 : d);
    if (better) { v1 = d; i1 = c; }
}
__device__ __forceinline__ void top2_merge(float& v1, int& i1, float& v2,
                                           float ov1, int oi1, float ov2) {
    const bool better = ov1 < v1;
    const float loser = better ? v1 : ov1;
    v2 = fminf(fminf(v2, ov2), loser);
    if (better) { v1 = ov1; i1 = oi1; }
}

// ---------------------------------------------------------------------------
// pre_cb: codebook -> Bhi/Blo tiled [nt][kt][128][32] bf16 + e2; also zeros
// the small control buffers (presence/rcnt/loss_delta).
// ---------------------------------------------------------------------------
__global__ __launch_bounds__(256)
void pre_cb(const float* __restrict__ cb, u16* __restrict__ Bhi, u16* __restrict__ Blo,
            float* __restrict__ e2, u32* __restrict__ presence,
            int* __restrict__ rcnt, float* __restrict__ ldel) {
    if (blockIdx.x < 16) presence[blockIdx.x * 256 + threadIdx.x] = 0u;
    if (blockIdx.x == 16 && threadIdx.x == 0) { rcnt[0] = 0; ldel[0] = 0.0f; }

    const int row  = blockIdx.x * 4 + (threadIdx.x >> 6);
    const int lane = threadIdx.x & 63;
    const float4 v = *(const float4*)(cb + (size_t)row * DIM + lane * 4);
    float s = v.x * v.x + v.y * v.y + v.z * v.z + v.w * v.w;
#pragma unroll
    for (int o = 32; o > 0; o >>= 1) s += __shfl_xor(s, o);
    if (lane == 0) e2[row] = s;

    const float vv[4] = {v.x, v.y, v.z, v.w};
    u16 h[4], l[4];
#pragma unroll
    for (int j = 0; j < 4; ++j) { h[j] = f2bf(vv[j]); l[j] = f2bf(vv[j] - bf2f(h[j])); }

    const int nt = row >> 7, pr = row & 127, kt = lane >> 3, kk = (lane & 7) * 4;
    const size_t dst = ((size_t)(nt * 8 + kt) * 128 + pr) * 32 + kk;
    *(uint2*)(Bhi + dst) = make_uint2((u32)h[0] | ((u32)h[1] << 16), (u32)h[2] | ((u32)h[3] << 16));
    *(uint2*)(Blo + dst) = make_uint2((u32)l[0] | ((u32)l[1] << 16), (u32)l[2] | ((u32)l[3] << 16));
}

// ---------------------------------------------------------------------------
// pre_z: z [16][256][1024] f32 -> Ahi/Alo tiled [mt][kt][128][32].
// One block per (mt, kt): grid 1024, fully parallel, one barrier.
// ---------------------------------------------------------------------------
__global__ __launch_bounds__(256)
void pre_z(const float* __restrict__ z, u16* __restrict__ Ahi, u16* __restrict__ Alo) {
    __shared__ u16 his[128 * 34], los[128 * 34];
    const int bid = blockIdx.x;               // 0..1023
    const int m = bid >> 3, kt = bid & 7;
    const int b = m >> 3, hw0 = (m & 7) * 128;
    const int t = threadIdx.x;
    const int p = t & 127, ch = t >> 7;

#pragma unroll
    for (int sub = 0; sub < 16; ++sub) {
        const int cl = sub * 2 + ch;
        const float v = z[(size_t)b * ZSTRIDE + (size_t)(kt * 32 + cl) * 1024 + hw0 + p];
        const u16 h = f2bf(v);
        his[p * 34 + cl] = h;
        los[p * 34 + cl] = f2bf(v - bf2f(h));
    }
    __syncthreads();
    const int p2 = t >> 1, half = (t & 1) * 16;
    const size_t dst = ((size_t)(m * 8 + kt) * 128 + p2) * 32 + half;
    u32 wh[8], wl[8];
#pragma unroll
    for (int j = 0; j < 8; ++j) {
        wh[j] = (u32)his[p2 * 34 + half + 2 * j] | ((u32)his[p2 * 34 + half + 2 * j + 1] << 16);
        wl[j] = (u32)los[p2 * 34 + half + 2 * j] | ((u32)los[p2 * 34 + half + 2 * j + 1] << 16);
    }
    *(uint4*)(Ahi + dst)     = make_uint4(wh[0], wh[1], wh[2], wh[3]);
    *(uint4*)(Ahi + dst + 8) = make_uint4(wh[4], wh[5], wh[6], wh[7]);
    *(uint4*)(Alo + dst)     = make_uint4(wl[0], wl[1], wl[2], wl[3]);
    *(uint4*)(Alo + dst + 8) = make_uint4(wl[4], wl[5], wl[6], wl[7]);
}

// ---------------------------------------------------------------------------
// gemm_argmin: per block 128 positions x 1024 codes (8 nt-tiles looped),
// BK=64 (2 kt-tiles staged/step -> 32 MFMA per barrier pair), lane-local
// running top-2 across all 8 tiles, ONE cross-lane merge per block.
// Grid 1024: ng = bid&7 (XCD-aligned code panel), mt = bid>>3.
// ---------------------------------------------------------------------------
__global__ __launch_bounds__(256)
void gemm_argmin(const u16* __restrict__ Ahi, const u16* __restrict__ Alo,
                 const u16* __restrict__ Bhi, const u16* __restrict__ Blo,
                 const float* __restrict__ e2,
                 float* __restrict__ wv1, int* __restrict__ wi1, float* __restrict__ wv2) {
    __shared__ u16 As[8192], Bs[8192];        // 2 kt-tiles each (16 KB each)
    __shared__ float lv1[256]; __shared__ int li1[256]; __shared__ float lv2[256];

    const int bid = blockIdx.x;
    const int ng  = bid & 7;                  // code-panel group -> same XCD
    const int mt  = bid >> 3;

    const int tid  = threadIdx.x;
    const int lane = tid & 63;
    const int wv   = tid >> 6;
    const int wr   = wv >> 1, wc = wv & 1;
    const int l15  = lane & 15, lq = lane >> 4;
    const int woff = (tid & 192) * 16;        // wave-uniform LDS byte base

    float rv1[16], rv2[16]; int ri1[16];
#pragma unroll
    for (int e = 0; e < 16; ++e) { rv1[e] = 3e38f; rv2[e] = 3e38f; ri1[e] = 0; }

    const size_t atile = (size_t)mt * 8 * 4096;

    for (int ntl = 0; ntl < 8; ++ntl) {
        const int nt = ng * 8 + ntl;
        const size_t btile = (size_t)nt * 8 * 4096;
        const int cbase = nt * 128 + wc * 64 + l15;
        float e2v[4];
#pragma unroll
        for (int ni = 0; ni < 4; ++ni) e2v[ni] = e2[cbase + ni * 16];

        f32x4 acc[4][4] = {};

        for (int ks = 0; ks < 12; ++ks) {     // ph = ks>>2, kt-pair = (ks&3)*2
            const int ph  = ks >> 2;
            const int kt2 = (ks & 3) * 2;
            const u16* Ap = (ph < 2 ? Ahi : Alo) + atile + (size_t)kt2 * 4096;
            const u16* Bp = (ph == 1 ? Blo : Bhi) + btile + (size_t)kt2 * 4096;
#pragma unroll
            for (int h = 0; h < 2; ++h) {
#pragma unroll
                for (int c = 0; c < 2; ++c) {
                    gload_lds16(Ap + h * 4096 + c * 2048 + tid * 8,
                                (char*)As + h * 8192 + c * 4096 + woff);
                    gload_lds16(Bp + h * 4096 + c * 2048 + tid * 8,
                                (char*)Bs + h * 8192 + c * 4096 + woff);
                }
            }
            __syncthreads();                  // drains vmcnt -> LDS tiles ready
#pragma unroll
            for (int ks2 = 0; ks2 < 2; ++ks2) {
                bf16x8 af[4], bfr[4];
#pragma unroll
                for (int i = 0; i < 4; ++i) {
                    af[i]  = *(const bf16x8*)(As + ks2 * 4096 + (wr * 64 + i * 16 + l15) * 32 + lq * 8);
                    bfr[i] = *(const bf16x8*)(Bs + ks2 * 4096 + (wc * 64 + i * 16 + l15) * 32 + lq * 8);
                }
#pragma unroll
                for (int i = 0; i < 4; ++i)
#pragma unroll
                    for (int j = 0; j < 4; ++j)
                        acc[i][j] = __builtin_amdgcn_mfma_f32_16x16x32_bf16(af[i], bfr[j], acc[i][j], 0, 0, 0);
            }
            __syncthreads();                  // all reads done before next stage
        }

        // lane-local push: d = e2 - 2S; C/D layout col=lane&15, row=(lane>>4)*4+reg
#pragma unroll
        for (int mi = 0; mi < 4; ++mi)
#pragma unroll
            for (int j = 0; j < 4; ++j) {
                const int e = mi * 4 + j;
#pragma unroll
                for (int ni = 0; ni < 4; ++ni) {
                    const float d = fmaf(-2.0f, acc[mi][ni][j], e2v[ni]);
                    top2_push(rv1[e], ri1[e], rv2[e], d, cbase + ni * 16);
                }
            }
    }

    // single cross-lane merge per block
#pragma unroll
    for (int mi = 0; mi < 4; ++mi)
#pragma unroll
        for (int j = 0; j < 4; ++j) {
            const int e = mi * 4 + j;
            float v1 = rv1[e], v2 = rv2[e]; int i1 = ri1[e];
#pragma unroll
            for (int off = 1; off <= 8; off <<= 1) {
                const float ov1 = __shfl_xor(v1, off);
                const int   oi1 = __shfl_xor(i1, off);
                const float ov2 = __shfl_xor(v2, off);
                top2_merge(v1, i1, v2, ov1, oi1, ov2);
            }
            if (l15 == 0) {
                const int row = wr * 64 + mi * 16 + lq * 4 + j;
                lv1[row * 2 + wc] = v1; li1[row * 2 + wc] = i1; lv2[row * 2 + wc] = v2;
            }
        }
    __syncthreads();
    if (tid < 128) {
        float v1 = lv1[tid * 2], v2 = lv2[tid * 2]; int i1 = li1[tid * 2];
        top2_merge(v1, i1, v2, lv1[tid * 2 + 1], li1[tid * 2 + 1], lv2[tid * 2 + 1]);
        const size_t o = (size_t)ng * NPOS + (size_t)mt * 128 + tid;
        wv1[o] = v1; wi1[o] = i1; wv2[o] = v2;
    }
}

// ---------------------------------------------------------------------------
// merge_output: fold 8 panel top-2s per position, margin test -> rescue list,
// then gather z_q + straight-through write + loss partials, all in one pass.
// ---------------------------------------------------------------------------
__global__ __launch_bounds__(256)
void merge_output(const float* __restrict__ wv1, const int* __restrict__ wi1,
                  const float* __restrict__ wv2,
                  const float* __restrict__ z, const float* __restrict__ cb,
                  float* __restrict__ out, float* __restrict__ out_idxf,
                  float* __restrict__ partial, u32* __restrict__ presence,
                  int* __restrict__ rcnt, int* __restrict__ rlist,
                  int* __restrict__ ws_idx) {
    __shared__ int codes[64];
    __shared__ float red[256];
    const int tile = blockIdx.x;
    const int b    = tile >> 4;
    const int hw0  = (tile & 15) * 64;
    const int tid  = threadIdx.x;
    const int m    = tid & 63;
    const int cg   = tid >> 6;

    if (cg == 0) {
        const int pos = tile * 64 + m;
        float v1 = 3e38f, v2 = 3e38f; int i1 = 0;
#pragma unroll
        for (int g = 0; g < 8; ++g) {
            const size_t o = (size_t)g * NPOS + pos;
            top2_merge(v1, i1, v2, wv1[o], wi1[o], wv2[o]);
        }
        codes[m]     = i1;
        ws_idx[pos]  = i1;
        out_idxf[pos] = (float)i1;
        if (v2 - v1 < TAU) {
            const int s = atomicAdd(rcnt, 1);
            rlist[s] = pos;
        } else {
            atomicOr(&presence[b * 256 + (i1 >> 5)], 1u << (i1 & 31));
        }
    }
    __syncthreads();

    const int code = codes[m];
    const float* crow = cb  + (size_t)code * DIM;
    const float* zb   = z   + (size_t)b * ZSTRIDE + hw0 + m;
    float*       ob   = out + (size_t)b * ZSTRIDE + hw0 + m;

    float lsum = 0.0f;
#pragma unroll
    for (int q = 0; q < 16; ++q) {
        const int c = (cg * 16 + q) * 4;
        const float4 e = *(const float4*)(crow + c);
        const float z0 = zb[(size_t)(c + 0) * 1024];
        const float z1 = zb[(size_t)(c + 1) * 1024];
        const float z2 = zb[(size_t)(c + 2) * 1024];
        const float z3 = zb[(size_t)(c + 3) * 1024];
        const float d0 = e.x - z0, d1 = e.y - z1, d2 = e.z - z2, d3 = e.w - z3;
        lsum += d0 * d0 + d1 * d1 + d2 * d2 + d3 * d3;
        ob[(size_t)(c + 0) * 1024] = z0 + d0;
        ob[(size_t)(c + 1) * 1024] = z1 + d1;
        ob[(size_t)(c + 2) * 1024] = z2 + d2;
        ob[(size_t)(c + 3) * 1024] = z3 + d3;
    }
    red[tid] = lsum;
    __syncthreads();
    for (int o = 128; o > 0; o >>= 1) {
        if (tid < o) red[tid] += red[tid + o];
        __syncthreads();
    }
    if (tid == 0) partial[tile] = red[0];
}

// ---------------------------------------------------------------------------
// rescue: exact fp32 full scan for flagged positions; patches idx, z_q row,
// presence, and a loss delta (expected ~0-100 entries).
// ---------------------------------------------------------------------------
__global__ __launch_bounds__(256)
void rescue_kernel(const float* __restrict__ z, const float* __restrict__ cb,
                   const float* __restrict__ e2, const int* __restrict__ rcnt,
                   const int* __restrict__ rlist, const int* __restrict__ ws_idx,
                   float* __restrict__ out_idxf, u32* __restrict__ presence,
                   float* __restrict__ out, float* __restrict__ ldel) {
    __shared__ float zvec[256];
    __shared__ float rv[256]; __shared__ int ri[256];
    const int n = rcnt[0];
    const int t = threadIdx.x;
    for (int e = blockIdx.x; e < n; e += gridDim.x) {
        const int pos = rlist[e];
        const int b = pos >> 10, hw = pos & 1023;
        __syncthreads();
        zvec[t] = z[(size_t)b * ZSTRIDE + (size_t)t * 1024 + hw];
        __syncthreads();
        float bv = 3e38f; int bi = 0x7fffffff;
        for (int c = t; c < NCODES; c += 256) {
            const float* cr = cb + (size_t)c * DIM;
            float dot = 0.f;
            for (int k = 0; k < DIM; k += 4) {
                const float4 cv = *(const float4*)(cr + k);
                dot = fmaf(zvec[k],     cv.x, dot);
                dot = fmaf(zvec[k + 1], cv.y, dot);
                dot = fmaf(zvec[k + 2], cv.z, dot);
                dot = fmaf(zvec[k + 3], cv.w, dot);
            }
            const float d = fmaf(-2.f, dot, e2[c]);
            if (d < bv) { bv = d; bi = c; }   // ascending c: strict < keeps smallest
        }
        rv[t] = bv; ri[t] = bi;
        __syncthreads();
        for (int o = 128; o > 0; o >>= 1) {
            if (t < o) {
                const float ov = rv[t + o]; const int oi = ri[t + o];
                if (ov < rv[t] || (ov == rv[t] && oi < ri[t])) { rv[t] = ov; ri[t] = oi; }
            }
            __syncthreads();
        }
        const int best = ri[0];
        const int old  = ws_idx[pos];
        if (t == 0) {
            out_idxf[pos] = (float)best;
            atomicOr(&presence[b * 256 + (best >> 5)], 1u << (best & 31));
        }
        if (best != old) {
            // patch z_q row + loss delta
            const float en = cb[(size_t)best * DIM + t];
            const float eo = cb[(size_t)old  * DIM + t];
            const float zv = zvec[t];
            const float dn = en - zv, dold = eo - zv;
            out[(size_t)b * ZSTRIDE + (size_t)t * 1024 + hw] = zv + dn;
            float dl = dn * dn - dold * dold;
#pragma unroll
            for (int o = 32; o > 0; o >>= 1) dl += __shfl_xor(dl, o);
            __syncthreads();
            if ((t & 63) == 0) rv[t >> 6] = dl;
            __syncthreads();
            if (t == 0) atomicAdd(ldel, rv[0] + rv[1] + rv[2] + rv[3]);
        }
        __syncthreads();
    }
}

// ---------------------------------------------------------------------------
__global__ __launch_bounds__(256)
void finalize_kernel(const float* __restrict__ partial,
                     const u32* __restrict__ presence,
                     const float* __restrict__ ldel,
                     float* __restrict__ out_loss, float* __restrict__ out_div) {
    __shared__ float sred[256];
    __shared__ int   ired[256];
    const int tid = threadIdx.x;
    float s = partial[tid];
    int cnt = 0;
    for (int w = tid; w < 16 * 256; w += 256) cnt += __popc(presence[w]);
    sred[tid] = s; ired[tid] = cnt;
    __syncthreads();
    for (int o = 128; o > 0; o >>= 1) {
        if (tid < o) { sred[tid] += sred[tid + o]; ired[tid] += ired[tid + o]; }
        __syncthreads();
    }
    if (tid == 0) {
        out_loss[0] = 1.25f * (sred[0] + ldel[0]) / (float)NELEM;
        out_div[0]  = (float)ired[0] / (float)NPOS;
    }
}

// ---------------------------------------------------------------------------
extern "C" void kernel_launch(void* const* d_in, const int* in_sizes, int n_in,
                              void* d_out, int out_size, void* d_ws, size_t ws_size,
                              hipStream_t stream) {
    const float* z  = (const float*)d_in[0];
    const float* cb = (const float*)d_in[1];
    float* out = (float*)d_out;
    char*  ws  = (char*)d_ws;

    u16*   Ahi = (u16*)(ws + WS_AHI);
    u16*   Alo = (u16*)(ws + WS_ALO);
    u16*   Bhi = (u16*)(ws + WS_BHI);
    u16*   Blo = (u16*)(ws + WS_BLO);
    float* e2  = (float*)(ws + WS_E2);
    float* wv1 = (float*)(ws + WS_WV1);
    int*   wi1 = (int*)(ws + WS_WI1);
    float* wv2 = (float*)(ws + WS_WV2);
    int*   ws_idx = (int*)(ws + WS_IDX);
    u32*   presence = (u32*)(ws + WS_PRES);
    int*   rcnt  = (int*)(ws + WS_RCNT);
    float* ldel  = (float*)(ws + WS_LDEL);
    int*   rlist = (int*)(ws + WS_RLIST);
    float* partial = (float*)(ws + WS_PART);

    float* out_zq   = out;
    float* out_idxf = out + NELEM;
    float* out_loss = out + NELEM + NPOS;
    float* out_div  = out + NELEM + NPOS + 1;

    pre_cb<<<NCODES / 4, 256, 0, stream>>>(cb, Bhi, Blo, e2, presence, rcnt, ldel);
    pre_z<<<1024, 256, 0, stream>>>(z, Ahi, Alo);
    gemm_argmin<<<1024, 256, 0, stream>>>(Ahi, Alo, Bhi, Blo, e2, wv1, wi1, wv2);
    merge_output<<<NPOS / 64, 256, 0, stream>>>(wv1, wi1, wv2, z, cb, out_zq, out_idxf,
                                                partial, presence, rcnt, rlist, ws_idx);
    rescue_kernel<<<64, 256, 0, stream>>>(z, cb, e2, rcnt, rlist, ws_idx,
                                          out_idxf, presence, out_zq, ldel);
    finalize_kernel<<<1, 256, 0, stream>>>(partial, presence, ldel, out_loss, out_div);
}

// Round 6
// 460.710 us; speedup vs baseline: 2.6044x; 1.1964x over previous
//
#include <hip/hip_runtime.h>
#include <cstdint>

typedef unsigned short u16;
typedef unsigned int   u32;
typedef __attribute__((ext_vector_type(8))) short bf16x8;
typedef __attribute__((ext_vector_type(4))) float f32x4;

// Problem constants
#define NPOS    16384
#define DIM     256
#define NCODES  8192
#define ZSTRIDE 262144     // 256*1024 floats per batch image
#define NELEM   4194304
#define TAU     6e-3f

// Tiled layout: [tile=(mt_or_nt*8+kt)][128 rows][32 k] u16, with 16B-chunk
// swizzle inside each 64B row: chunk q stored at q ^ ((row>>1)&3).
// Readers and writers both apply it; global_load_lds copies linearly.

// ws layout (bytes), total ~27 MB
#define WS_AHI    0u           // u16[16384*256] tiled [128 mt][8 kt][128][32]
#define WS_ALO    8388608u
#define WS_BHI    16777216u    // u16[8192*256]  tiled [64 nt][8 kt][128][32]
#define WS_BLO    20971520u
#define WS_E2     25165824u    // f32[8192]
#define WS_WV1    25198592u    // f32[8][16384]
#define WS_WI1    25722880u    // i32[8][16384]
#define WS_WV2    26247168u    // f32[8][16384]
#define WS_IDX    26771456u    // i32[16384]
#define WS_PRES   26836992u    // u32[16*256]
#define WS_RCNT   26853376u    // i32
#define WS_LDEL   26853380u    // f32 loss delta
#define WS_RLIST  26853632u    // i32[16384]
#define WS_PART   26919168u    // f32[256]

__device__ __forceinline__ u16 f2bf(float x) {   // round-to-nearest-even bf16
    u32 u = __float_as_uint(x);
    return (u16)((u + 0x7FFFu + ((u >> 16) & 1u)) >> 16);
}
__device__ __forceinline__ float bf2f(u16 h) { return __uint_as_float((u32)h << 16); }

__device__ __forceinline__ void gload_lds16(const void* g, void* l) {
    __builtin_amdgcn_global_load_lds(
        (const __attribute__((address_space(1))) void*)g,
        (__attribute__((address_space(3))) void*)l, 16, 0, 0);
}

// top-2 without index tie-break: an exact tie leaves v2 == v1 -> margin 0 -> rescued
__device__ __forceinline__ void top2_push(float& v1, int& i1, float& v2, float d, int c) {
    const bool better = d < v1;
    v2 = fminf(v2, fmaxf(d, v1));          // new 2nd-best candidate
    v1 = fminf(v1, d);
    if (better) i1 = c;
}
__device__ __forceinline__ void top2_merge(float& v1, int& i1, float& v2,
                                           float ov1, int oi1, float ov2) {
    const bool better = ov1 < v1;
    v2 = fminf(fminf(v2, ov2), fmaxf(v1, ov1));
    v1 = fminf(v1, ov1);
    if (better) i1 = oi1;
}

// ---------------------------------------------------------------------------
// preprocess: blocks [0,2048): codebook -> Bhi/Blo (swizzled tiles) + e2 +
// zero control buffers.  Blocks [2048,3072): z -> Ahi/Alo (swizzled tiles).
// ---------------------------------------------------------------------------
__global__ __launch_bounds__(256)
void preprocess(const float* __restrict__ cb, const float* __restrict__ z,
                u16* __restrict__ Bhi, u16* __restrict__ Blo,
                u16* __restrict__ Ahi, u16* __restrict__ Alo,
                float* __restrict__ e2, u32* __restrict__ presence,
                int* __restrict__ rcnt, float* __restrict__ ldel) {
    __shared__ u16 his[128 * 34], los[128 * 34];
    const int bid = blockIdx.x;
    const int t   = threadIdx.x;

    if (bid < 2048) {
        if (bid < 16) presence[bid * 256 + t] = 0u;
        if (bid == 16 && t == 0) { rcnt[0] = 0; ldel[0] = 0.0f; }

        const int row  = bid * 4 + (t >> 6);
        const int lane = t & 63;
        const float4 v = *(const float4*)(cb + (size_t)row * DIM + lane * 4);
        float s = v.x * v.x + v.y * v.y + v.z * v.z + v.w * v.w;
#pragma unroll
        for (int o = 32; o > 0; o >>= 1) s += __shfl_xor(s, o);
        if (lane == 0) e2[row] = s;

        const float vv[4] = {v.x, v.y, v.z, v.w};
        u16 h[4], l[4];
#pragma unroll
        for (int j = 0; j < 4; ++j) { h[j] = f2bf(vv[j]); l[j] = f2bf(vv[j] - bf2f(h[j])); }

        const int nt = row >> 7, pr = row & 127, kt = lane >> 3;
        const int q  = (lane & 7) >> 1, off = (lane & 1) * 4;
        const int sw = (pr >> 1) & 3;
        const size_t dst = ((size_t)(nt * 8 + kt) * 128 + pr) * 32 + ((q ^ sw) << 3) + off;
        *(uint2*)(Bhi + dst) = make_uint2((u32)h[0] | ((u32)h[1] << 16), (u32)h[2] | ((u32)h[3] << 16));
        *(uint2*)(Blo + dst) = make_uint2((u32)l[0] | ((u32)l[1] << 16), (u32)l[2] | ((u32)l[3] << 16));
        return;
    }

    // z part: one block per (mt, kt)
    const int zb = bid - 2048;                // 0..1023
    const int m = zb >> 3, kt = zb & 7;
    const int b = m >> 3, hw0 = (m & 7) * 128;
    const int p = t & 127, ch = t >> 7;

#pragma unroll
    for (int sub = 0; sub < 16; ++sub) {
        const int cl = sub * 2 + ch;
        const float v = z[(size_t)b * ZSTRIDE + (size_t)(kt * 32 + cl) * 1024 + hw0 + p];
        const u16 h = f2bf(v);
        his[p * 34 + cl] = h;
        los[p * 34 + cl] = f2bf(v - bf2f(h));
    }
    __syncthreads();
    const int p2 = t >> 1, c0 = (t & 1) * 2;
    const int sw = (p2 >> 1) & 3;
    const size_t base = ((size_t)(m * 8 + kt) * 128 + p2) * 32;
    u32 wh[8], wl[8];
    const int half = c0 * 8;
#pragma unroll
    for (int j = 0; j < 8; ++j) {
        wh[j] = (u32)his[p2 * 34 + half + 2 * j] | ((u32)his[p2 * 34 + half + 2 * j + 1] << 16);
        wl[j] = (u32)los[p2 * 34 + half + 2 * j] | ((u32)los[p2 * 34 + half + 2 * j + 1] << 16);
    }
    *(uint4*)(Ahi + base + (((c0 + 0) ^ sw) << 3)) = make_uint4(wh[0], wh[1], wh[2], wh[3]);
    *(uint4*)(Ahi + base + (((c0 + 1) ^ sw) << 3)) = make_uint4(wh[4], wh[5], wh[6], wh[7]);
    *(uint4*)(Alo + base + (((c0 + 0) ^ sw) << 3)) = make_uint4(wl[0], wl[1], wl[2], wl[3]);
    *(uint4*)(Alo + base + (((c0 + 1) ^ sw) << 3)) = make_uint4(wl[4], wl[5], wl[6], wl[7]);
}

// ---------------------------------------------------------------------------
// gemm_argmin: per block 128 positions x 1024 codes.  64 steps of (nt,kt);
// each step stages {Ahi,Alo,Bhi,Blo}[kt] (32KB) double-buffered, prefetch
// issued BEFORE compute, 48 MFMA/step (3 fused split-precision phases
// sharing staged tiles), swizzled conflict-free ds_read_b128.  Lane-local
// top-2, one cross-lane merge per block.
// ---------------------------------------------------------------------------
__global__ __launch_bounds__(256, 2)
void gemm_argmin(const u16* __restrict__ Ahi, const u16* __restrict__ Alo,
                 const u16* __restrict__ Bhi, const u16* __restrict__ Blo,
                 const float* __restrict__ e2,
                 float* __restrict__ wv1, int* __restrict__ wi1, float* __restrict__ wv2) {
    __shared__ u16 sbuf[2][4][4096];          // [dbuf][Ahi,Alo,Bhi,Blo][8KB]
    __shared__ float lv1[256]; __shared__ int li1[256]; __shared__ float lv2[256];

    const int bid = blockIdx.x;
    const int ng  = bid & 7;                  // code-panel group -> same XCD
    const int mt  = bid >> 3;

    const int tid  = threadIdx.x;
    const int lane = tid & 63;
    const int wvi  = tid >> 6;
    const int wr   = wvi >> 1, wc = wvi & 1;
    const int l15  = lane & 15, lq = lane >> 4;
    const int woff = (tid & 192) * 16;        // wave-uniform LDS byte base
    const int src  = tid * 8;                 // u16 offset within 4KB half
    const int sel  = (l15 >> 1) & 3;          // row-swizzle selector (row bits 1:2)
    const int ka   = ((lq ^ sel) << 3);       // swizzled k-chunk elem offset

#define FRAG(base, row) (*(const bf16x8*)((base) + (row) * 32 + ka))
#define STAGE(bq, ss_) do {                                                     \
        const int nt_ = ng * 8 + ((ss_) >> 3), kt_ = (ss_) & 7;                 \
        const u16* Ah_ = Ahi + (size_t)(mt * 8 + kt_) * 4096;                   \
        const u16* Al_ = Alo + (size_t)(mt * 8 + kt_) * 4096;                   \
        const u16* Bh_ = Bhi + (size_t)(nt_ * 8 + kt_) * 4096;                  \
        const u16* Bl_ = Blo + (size_t)(nt_ * 8 + kt_) * 4096;                  \
        gload_lds16(Ah_ + src,        (char*)&sbuf[bq][0][0] + woff);           \
        gload_lds16(Ah_ + 2048 + src, (char*)&sbuf[bq][0][0] + 4096 + woff);    \
        gload_lds16(Al_ + src,        (char*)&sbuf[bq][1][0] + woff);           \
        gload_lds16(Al_ + 2048 + src, (char*)&sbuf[bq][1][0] + 4096 + woff);    \
        gload_lds16(Bh_ + src,        (char*)&sbuf[bq][2][0] + woff);           \
        gload_lds16(Bh_ + 2048 + src, (char*)&sbuf[bq][2][0] + 4096 + woff);    \
        gload_lds16(Bl_ + src,        (char*)&sbuf[bq][3][0] + woff);           \
        gload_lds16(Bl_ + 2048 + src, (char*)&sbuf[bq][3][0] + 4096 + woff);    \
    } while (0)

    float rv1[16], rv2[16]; int ri1[16];
#pragma unroll
    for (int e = 0; e < 16; ++e) { rv1[e] = 3e38f; rv2[e] = 3e38f; ri1[e] = 0; }

    f32x4 acc[4][4] = {};
    float e2v[4];
    int cbase = 0;

    STAGE(0, 0);
    __syncthreads();

    for (int ss = 0; ss < 64; ++ss) {
        const int cur = ss & 1;
        if (ss < 63) STAGE(cur ^ 1, ss + 1);  // prefetch overlaps compute

        if ((ss & 7) == 0) {                  // new nt: load e2 for epilogue
            const int nt = ng * 8 + (ss >> 3);
            cbase = nt * 128 + wc * 64 + l15;
#pragma unroll
            for (int ni = 0; ni < 4; ++ni) e2v[ni] = e2[cbase + ni * 16];
        }

        const u16* Ah = &sbuf[cur][0][0];
        const u16* Al = &sbuf[cur][1][0];
        const u16* Bh = &sbuf[cur][2][0];
        const u16* Bl = &sbuf[cur][3][0];

        bf16x8 ah[4], bh[4], xx[4];
#pragma unroll
        for (int i = 0; i < 4; ++i) ah[i] = FRAG(Ah, wr * 64 + i * 16 + l15);
#pragma unroll
        for (int i = 0; i < 4; ++i) bh[i] = FRAG(Bh, wc * 64 + i * 16 + l15);
#pragma unroll
        for (int i = 0; i < 4; ++i)
#pragma unroll
            for (int j = 0; j < 4; ++j)
                acc[i][j] = __builtin_amdgcn_mfma_f32_16x16x32_bf16(ah[i], bh[j], acc[i][j], 0, 0, 0);
#pragma unroll
        for (int i = 0; i < 4; ++i) xx[i] = FRAG(Bl, wc * 64 + i * 16 + l15);
#pragma unroll
        for (int i = 0; i < 4; ++i)
#pragma unroll
            for (int j = 0; j < 4; ++j)
                acc[i][j] = __builtin_amdgcn_mfma_f32_16x16x32_bf16(ah[i], xx[j], acc[i][j], 0, 0, 0);
#pragma unroll
        for (int i = 0; i < 4; ++i) xx[i] = FRAG(Al, wr * 64 + i * 16 + l15);
#pragma unroll
        for (int i = 0; i < 4; ++i)
#pragma unroll
            for (int j = 0; j < 4; ++j)
                acc[i][j] = __builtin_amdgcn_mfma_f32_16x16x32_bf16(xx[i], bh[j], acc[i][j], 0, 0, 0);

        if ((ss & 7) == 7) {                  // end of nt: push top-2, THEN reset acc
#pragma unroll
            for (int mi = 0; mi < 4; ++mi)
#pragma unroll
                for (int j = 0; j < 4; ++j) {
                    const int e = mi * 4 + j;
#pragma unroll
                    for (int ni = 0; ni < 4; ++ni) {
                        const float d = fmaf(-2.0f, acc[mi][ni][j], e2v[ni]);
                        top2_push(rv1[e], ri1[e], rv2[e], d, cbase + ni * 16);
                    }
                }
            // reset AFTER all 16 rows are pushed (R4 bug: reset inside j-loop
            // zeroed components j=1..3 before they were pushed)
#pragma unroll
            for (int mi = 0; mi < 4; ++mi)
#pragma unroll
                for (int ni = 0; ni < 4; ++ni)
                    acc[mi][ni] = f32x4{0.f, 0.f, 0.f, 0.f};
        }
        __syncthreads();                      // drains vmcnt -> next buf ready, cur released
    }

    // single cross-lane merge per block
#pragma unroll
    for (int mi = 0; mi < 4; ++mi)
#pragma unroll
        for (int j = 0; j < 4; ++j) {
            const int e = mi * 4 + j;
            float v1 = rv1[e], v2 = rv2[e]; int i1 = ri1[e];
#pragma unroll
            for (int off = 1; off <= 8; off <<= 1) {
                const float ov1 = __shfl_xor(v1, off);
                const int   oi1 = __shfl_xor(i1, off);
                const float ov2 = __shfl_xor(v2, off);
                top2_merge(v1, i1, v2, ov1, oi1, ov2);
            }
            if (l15 == 0) {
                const int row = wr * 64 + mi * 16 + lq * 4 + j;
                lv1[row * 2 + wc] = v1; li1[row * 2 + wc] = i1; lv2[row * 2 + wc] = v2;
            }
        }
    __syncthreads();
    if (tid < 128) {
        float v1 = lv1[tid * 2], v2 = lv2[tid * 2]; int i1 = li1[tid * 2];
        top2_merge(v1, i1, v2, lv1[tid * 2 + 1], li1[tid * 2 + 1], lv2[tid * 2 + 1]);
        const size_t o = (size_t)ng * NPOS + (size_t)mt * 128 + tid;
        wv1[o] = v1; wi1[o] = i1; wv2[o] = v2;
    }
#undef FRAG
#undef STAGE
}

// ---------------------------------------------------------------------------
// merge_output: fold 8 panel top-2s per position, margin test -> rescue list,
// then gather z_q + straight-through write + loss partials.
// ---------------------------------------------------------------------------
__global__ __launch_bounds__(256)
void merge_output(const float* __restrict__ wv1, const int* __restrict__ wi1,
                  const float* __restrict__ wv2,
                  const float* __restrict__ z, const float* __restrict__ cb,
                  float* __restrict__ out, float* __restrict__ out_idxf,
                  float* __restrict__ partial, u32* __restrict__ presence,
                  int* __restrict__ rcnt, int* __restrict__ rlist,
                  int* __restrict__ ws_idx) {
    __shared__ int codes[64];
    __shared__ float red[256];
    const int tile = blockIdx.x;
    const int b    = tile >> 4;
    const int hw0  = (tile & 15) * 64;
    const int tid  = threadIdx.x;
    const int m    = tid & 63;
    const int cg   = tid >> 6;

    if (cg == 0) {
        const int pos = tile * 64 + m;
        float v1 = 3e38f, v2 = 3e38f; int i1 = 0;
#pragma unroll
        for (int g = 0; g < 8; ++g) {
            const size_t o = (size_t)g * NPOS + pos;
            top2_merge(v1, i1, v2, wv1[o], wi1[o], wv2[o]);
        }
        codes[m]      = i1;
        ws_idx[pos]   = i1;
        out_idxf[pos] = (float)i1;
        if (v2 - v1 < TAU) {
            const int s = atomicAdd(rcnt, 1);
            rlist[s] = pos;
        } else {
            atomicOr(&presence[b * 256 + (i1 >> 5)], 1u << (i1 & 31));
        }
    }
    __syncthreads();

    const int code = codes[m];
    const float* crow = cb  + (size_t)code * DIM;
    const float* zb   = z   + (size_t)b * ZSTRIDE + hw0 + m;
    float*       ob   = out + (size_t)b * ZSTRIDE + hw0 + m;

    float lsum = 0.0f;
#pragma unroll
    for (int q = 0; q < 16; ++q) {
        const int c = (cg * 16 + q) * 4;
        const float4 e = *(const float4*)(crow + c);
        const float z0 = zb[(size_t)(c + 0) * 1024];
        const float z1 = zb[(size_t)(c + 1) * 1024];
        const float z2 = zb[(size_t)(c + 2) * 1024];
        const float z3 = zb[(size_t)(c + 3) * 1024];
        const float d0 = e.x - z0, d1 = e.y - z1, d2 = e.z - z2, d3 = e.w - z3;
        lsum += d0 * d0 + d1 * d1 + d2 * d2 + d3 * d3;
        ob[(size_t)(c + 0) * 1024] = z0 + d0;
        ob[(size_t)(c + 1) * 1024] = z1 + d1;
        ob[(size_t)(c + 2) * 1024] = z2 + d2;
        ob[(size_t)(c + 3) * 1024] = z3 + d3;
    }
    red[tid] = lsum;
    __syncthreads();
    for (int o = 128; o > 0; o >>= 1) {
        if (tid < o) red[tid] += red[tid + o];
        __syncthreads();
    }
    if (tid == 0) partial[tile] = red[0];
}

// ---------------------------------------------------------------------------
// rescue: exact fp32 full scan for flagged positions; patches idx, z_q row,
// presence, and a loss delta (expected ~0-100 entries).
// ---------------------------------------------------------------------------
__global__ __launch_bounds__(256)
void rescue_kernel(const float* __restrict__ z, const float* __restrict__ cb,
                   const float* __restrict__ e2, const int* __restrict__ rcnt,
                   const int* __restrict__ rlist, const int* __restrict__ ws_idx,
                   float* __restrict__ out_idxf, u32* __restrict__ presence,
                   float* __restrict__ out, float* __restrict__ ldel) {
    __shared__ float zvec[256];
    __shared__ float rv[256]; __shared__ int ri[256];
    const int n = rcnt[0];
    const int t = threadIdx.x;
    for (int e = blockIdx.x; e < n; e += gridDim.x) {
        const int pos = rlist[e];
        const int b = pos >> 10, hw = pos & 1023;
        __syncthreads();
        zvec[t] = z[(size_t)b * ZSTRIDE + (size_t)t * 1024 + hw];
        __syncthreads();
        float bv = 3e38f; int bi = 0x7fffffff;
        for (int c = t; c < NCODES; c += 256) {
            const float* cr = cb + (size_t)c * DIM;
            float dot = 0.f;
            for (int k = 0; k < DIM; k += 4) {
                const float4 cv = *(const float4*)(cr + k);
                dot = fmaf(zvec[k],     cv.x, dot);
                dot = fmaf(zvec[k + 1], cv.y, dot);
                dot = fmaf(zvec[k + 2], cv.z, dot);
                dot = fmaf(zvec[k + 3], cv.w, dot);
            }
            const float d = fmaf(-2.f, dot, e2[c]);
            if (d < bv) { bv = d; bi = c; }   // ascending c: strict < keeps smallest
        }
        rv[t] = bv; ri[t] = bi;
        __syncthreads();
        for (int o = 128; o > 0; o >>= 1) {
            if (t < o) {
                const float ov = rv[t + o]; const int oi = ri[t + o];
                if (ov < rv[t] || (ov == rv[t] && oi < ri[t])) { rv[t] = ov; ri[t] = oi; }
            }
            __syncthreads();
        }
        const int best = ri[0];
        const int old  = ws_idx[pos];
        if (t == 0) {
            out_idxf[pos] = (float)best;
            atomicOr(&presence[b * 256 + (best >> 5)], 1u << (best & 31));
        }
        if (best != old) {
            const float en = cb[(size_t)best * DIM + t];
            const float eo = cb[(size_t)old  * DIM + t];
            const float zv = zvec[t];
            const float dn = en - zv, dold = eo - zv;
            out[(size_t)b * ZSTRIDE + (size_t)t * 1024 + hw] = zv + dn;
            float dl = dn * dn - dold * dold;
#pragma unroll
            for (int o = 32; o > 0; o >>= 1) dl += __shfl_xor(dl, o);
            __syncthreads();
            if ((t & 63) == 0) rv[t >> 6] = dl;
            __syncthreads();
            if (t == 0) atomicAdd(ldel, rv[0] + rv[1] + rv[2] + rv[3]);
        }
        __syncthreads();
    }
}

// ---------------------------------------------------------------------------
__global__ __launch_bounds__(256)
void finalize_kernel(const float* __restrict__ partial,
                     const u32* __restrict__ presence,
                     const float* __restrict__ ldel,
                     float* __restrict__ out_loss, float* __restrict__ out_div) {
    __shared__ float sred[256];
    __shared__ int   ired[256];
    const int tid = threadIdx.x;
    float s = partial[tid];
    int cnt = 0;
    for (int w = tid; w < 16 * 256; w += 256) cnt += __popc(presence[w]);
    sred[tid] = s; ired[tid] = cnt;
    __syncthreads();
    for (int o = 128; o > 0; o >>= 1) {
        if (tid < o) { sred[tid] += sred[tid + o]; ired[tid] += ired[tid + o]; }
        __syncthreads();
    }
    if (tid == 0) {
        out_loss[0] = 1.25f * (sred[0] + ldel[0]) / (float)NELEM;
        out_div[0]  = (float)ired[0] / (float)NPOS;
    }
}

// ---------------------------------------------------------------------------
extern "C" void kernel_launch(void* const* d_in, const int* in_sizes, int n_in,
                              void* d_out, int out_size, void* d_ws, size_t ws_size,
                              hipStream_t stream) {
    const float* z  = (const float*)d_in[0];
    const float* cb = (const float*)d_in[1];
    float* out = (float*)d_out;
    char*  ws  = (char*)d_ws;

    u16*   Ahi = (u16*)(ws + WS_AHI);
    u16*   Alo = (u16*)(ws + WS_ALO);
    u16*   Bhi = (u16*)(ws + WS_BHI);
    u16*   Blo = (u16*)(ws + WS_BLO);
    float* e2  = (float*)(ws + WS_E2);
    float* wv1 = (float*)(ws + WS_WV1);
    int*   wi1 = (int*)(ws + WS_WI1);
    float* wv2 = (float*)(ws + WS_WV2);
    int*   ws_idx = (int*)(ws + WS_IDX);
    u32*   presence = (u32*)(ws + WS_PRES);
    int*   rcnt  = (int*)(ws + WS_RCNT);
    float* ldel  = (float*)(ws + WS_LDEL);
    int*   rlist = (int*)(ws + WS_RLIST);
    float* partial = (float*)(ws + WS_PART);

    float* out_zq   = out;
    float* out_idxf = out + NELEM;
    float* out_loss = out + NELEM + NPOS;
    float* out_div  = out + NELEM + NPOS + 1;

    preprocess<<<3072, 256, 0, stream>>>(cb, z, Bhi, Blo, Ahi, Alo, e2, presence, rcnt, ldel);
    gemm_argmin<<<1024, 256, 0, stream>>>(Ahi, Alo, Bhi, Blo, e2, wv1, wi1, wv2);
    merge_output<<<NPOS / 64, 256, 0, stream>>>(wv1, wi1, wv2, z, cb, out_zq, out_idxf,
                                                partial, presence, rcnt, rlist, ws_idx);
    rescue_kernel<<<64, 256, 0, stream>>>(z, cb, e2, rcnt, rlist, ws_idx,
                                          out_idxf, presence, out_zq, ldel);
    finalize_kernel<<<1, 256, 0, stream>>>(partial, presence, ldel, out_loss, out_div);
}

// Round 7
// 256.389 us; speedup vs baseline: 4.6798x; 1.7969x over previous
//
#include <hip/hip_runtime.h>
#include <cstdint>

typedef unsigned short u16;
typedef unsigned int   u32;
typedef __attribute__((ext_vector_type(8))) short bf16x8;
typedef __attribute__((ext_vector_type(4))) float f32x4;

// Problem constants
#define NPOS    16384
#define DIM     256
#define NCODES  8192
#define ZSTRIDE 262144     // 256*1024 floats per batch image
#define NELEM   4194304
#define TAU     6e-3f
#define RCH     32         // rescue chunks per position (8192/256)

// Tiled layout: [tile=(mt_or_nt*8+kt)][128 rows][32 k] u16, with 16B-chunk
// swizzle inside each 64B row: chunk q stored at q ^ ((row>>1)&3).

// ws layout (bytes), total ~30 MB
#define WS_AHI    0u           // u16[16384*256] tiled [128 mt][8 kt][128][32]
#define WS_ALO    8388608u
#define WS_BHI    16777216u    // u16[8192*256]  tiled [64 nt][8 kt][128][32]
#define WS_BLO    20971520u
#define WS_E2     25165824u    // f32[8192]
#define WS_WV1    25198592u    // f32[8][16384]
#define WS_WI1    25722880u    // i32[8][16384]
#define WS_WV2    26247168u    // f32[8][16384]
#define WS_IDX    26771456u    // i32[16384]
#define WS_PRES   26836992u    // u32[16*256]
#define WS_RCNT   26853376u    // i32
#define WS_LDEL   26853380u    // f32 loss delta
#define WS_RLIST  26853632u    // i32[16384]
#define WS_PART   26919168u    // f32[256]
#define WS_RBV    26920448u    // f32[16384*32] rescue per-chunk best val (2MB)
#define WS_RBI    29017600u    // i32[16384*32] rescue per-chunk best idx (2MB)

__device__ __forceinline__ u16 f2bf(float x) {   // round-to-nearest-even bf16
    u32 u = __float_as_uint(x);
    return (u16)((u + 0x7FFFu + ((u >> 16) & 1u)) >> 16);
}
__device__ __forceinline__ float bf2f(u16 h) { return __uint_as_float((u32)h << 16); }

__device__ __forceinline__ void gload_lds16(const void* g, void* l) {
    __builtin_amdgcn_global_load_lds(
        (const __attribute__((address_space(1))) void*)g,
        (__attribute__((address_space(3))) void*)l, 16, 0, 0);
}

// top-2 without index tie-break: an exact tie leaves v2 == v1 -> margin 0 -> rescued
__device__ __forceinline__ void top2_push(float& v1, int& i1, float& v2, float d, int c) {
    const bool better = d < v1;
    v2 = fminf(v2, fmaxf(d, v1));
    v1 = fminf(v1, d);
    if (better) i1 = c;
}
__device__ __forceinline__ void top2_merge(float& v1, int& i1, float& v2,
                                           float ov1, int oi1, float ov2) {
    const bool better = ov1 < v1;
    v2 = fminf(fminf(v2, ov2), fmaxf(v1, ov1));
    v1 = fminf(v1, ov1);
    if (better) i1 = oi1;
}

// ---------------------------------------------------------------------------
// preprocess: blocks [0,2048): codebook -> Bhi/Blo (swizzled tiles) + e2 +
// zero control buffers.  Blocks [2048,3072): z -> Ahi/Alo (swizzled tiles).
// ---------------------------------------------------------------------------
__global__ __launch_bounds__(256)
void preprocess(const float* __restrict__ cb, const float* __restrict__ z,
                u16* __restrict__ Bhi, u16* __restrict__ Blo,
                u16* __restrict__ Ahi, u16* __restrict__ Alo,
                float* __restrict__ e2, u32* __restrict__ presence,
                int* __restrict__ rcnt, float* __restrict__ ldel) {
    __shared__ u16 his[128 * 34], los[128 * 34];
    const int bid = blockIdx.x;
    const int t   = threadIdx.x;

    if (bid < 2048) {
        if (bid < 16) presence[bid * 256 + t] = 0u;
        if (bid == 16 && t == 0) { rcnt[0] = 0; ldel[0] = 0.0f; }

        const int row  = bid * 4 + (t >> 6);
        const int lane = t & 63;
        const float4 v = *(const float4*)(cb + (size_t)row * DIM + lane * 4);
        float s = v.x * v.x + v.y * v.y + v.z * v.z + v.w * v.w;
#pragma unroll
        for (int o = 32; o > 0; o >>= 1) s += __shfl_xor(s, o);
        if (lane == 0) e2[row] = s;

        const float vv[4] = {v.x, v.y, v.z, v.w};
        u16 h[4], l[4];
#pragma unroll
        for (int j = 0; j < 4; ++j) { h[j] = f2bf(vv[j]); l[j] = f2bf(vv[j] - bf2f(h[j])); }

        const int nt = row >> 7, pr = row & 127, kt = lane >> 3;
        const int q  = (lane & 7) >> 1, off = (lane & 1) * 4;
        const int sw = (pr >> 1) & 3;
        const size_t dst = ((size_t)(nt * 8 + kt) * 128 + pr) * 32 + ((q ^ sw) << 3) + off;
        *(uint2*)(Bhi + dst) = make_uint2((u32)h[0] | ((u32)h[1] << 16), (u32)h[2] | ((u32)h[3] << 16));
        *(uint2*)(Blo + dst) = make_uint2((u32)l[0] | ((u32)l[1] << 16), (u32)l[2] | ((u32)l[3] << 16));
        return;
    }

    // z part: one block per (mt, kt)
    const int zb = bid - 2048;                // 0..1023
    const int m = zb >> 3, kt = zb & 7;
    const int b = m >> 3, hw0 = (m & 7) * 128;
    const int p = t & 127, ch = t >> 7;

#pragma unroll
    for (int sub = 0; sub < 16; ++sub) {
        const int cl = sub * 2 + ch;
        const float v = z[(size_t)b * ZSTRIDE + (size_t)(kt * 32 + cl) * 1024 + hw0 + p];
        const u16 h = f2bf(v);
        his[p * 34 + cl] = h;
        los[p * 34 + cl] = f2bf(v - bf2f(h));
    }
    __syncthreads();
    const int p2 = t >> 1, c0 = (t & 1) * 2;
    const int sw = (p2 >> 1) & 3;
    const size_t base = ((size_t)(m * 8 + kt) * 128 + p2) * 32;
    u32 wh[8], wl[8];
    const int half = c0 * 8;
#pragma unroll
    for (int j = 0; j < 8; ++j) {
        wh[j] = (u32)his[p2 * 34 + half + 2 * j] | ((u32)his[p2 * 34 + half + 2 * j + 1] << 16);
        wl[j] = (u32)los[p2 * 34 + half + 2 * j] | ((u32)los[p2 * 34 + half + 2 * j + 1] << 16);
    }
    *(uint4*)(Ahi + base + (((c0 + 0) ^ sw) << 3)) = make_uint4(wh[0], wh[1], wh[2], wh[3]);
    *(uint4*)(Ahi + base + (((c0 + 1) ^ sw) << 3)) = make_uint4(wh[4], wh[5], wh[6], wh[7]);
    *(uint4*)(Alo + base + (((c0 + 0) ^ sw) << 3)) = make_uint4(wl[0], wl[1], wl[2], wl[3]);
    *(uint4*)(Alo + base + (((c0 + 1) ^ sw) << 3)) = make_uint4(wl[4], wl[5], wl[6], wl[7]);
}

// ---------------------------------------------------------------------------
// gemm_argmin: unchanged from R6 (passed, absmax 0).
// ---------------------------------------------------------------------------
__global__ __launch_bounds__(256, 2)
void gemm_argmin(const u16* __restrict__ Ahi, const u16* __restrict__ Alo,
                 const u16* __restrict__ Bhi, const u16* __restrict__ Blo,
                 const float* __restrict__ e2,
                 float* __restrict__ wv1, int* __restrict__ wi1, float* __restrict__ wv2) {
    __shared__ u16 sbuf[2][4][4096];          // [dbuf][Ahi,Alo,Bhi,Blo][8KB]
    __shared__ float lv1[256]; __shared__ int li1[256]; __shared__ float lv2[256];

    const int bid = blockIdx.x;
    const int ng  = bid & 7;                  // code-panel group -> same XCD
    const int mt  = bid >> 3;

    const int tid  = threadIdx.x;
    const int lane = tid & 63;
    const int wvi  = tid >> 6;
    const int wr   = wvi >> 1, wc = wvi & 1;
    const int l15  = lane & 15, lq = lane >> 4;
    const int woff = (tid & 192) * 16;        // wave-uniform LDS byte base
    const int src  = tid * 8;                 // u16 offset within 4KB half
    const int sel  = (l15 >> 1) & 3;          // row-swizzle selector (row bits 1:2)
    const int ka   = ((lq ^ sel) << 3);       // swizzled k-chunk elem offset

#define FRAG(base, row) (*(const bf16x8*)((base) + (row) * 32 + ka))
#define STAGE(bq, ss_) do {                                                     \
        const int nt_ = ng * 8 + ((ss_) >> 3), kt_ = (ss_) & 7;                 \
        const u16* Ah_ = Ahi + (size_t)(mt * 8 + kt_) * 4096;                   \
        const u16* Al_ = Alo + (size_t)(mt * 8 + kt_) * 4096;                   \
        const u16* Bh_ = Bhi + (size_t)(nt_ * 8 + kt_) * 4096;                  \
        const u16* Bl_ = Blo + (size_t)(nt_ * 8 + kt_) * 4096;                  \
        gload_lds16(Ah_ + src,        (char*)&sbuf[bq][0][0] + woff);           \
        gload_lds16(Ah_ + 2048 + src, (char*)&sbuf[bq][0][0] + 4096 + woff);    \
        gload_lds16(Al_ + src,        (char*)&sbuf[bq][1][0] + woff);           \
        gload_lds16(Al_ + 2048 + src, (char*)&sbuf[bq][1][0] + 4096 + woff);    \
        gload_lds16(Bh_ + src,        (char*)&sbuf[bq][2][0] + woff);           \
        gload_lds16(Bh_ + 2048 + src, (char*)&sbuf[bq][2][0] + 4096 + woff);    \
        gload_lds16(Bl_ + src,        (char*)&sbuf[bq][3][0] + woff);           \
        gload_lds16(Bl_ + 2048 + src, (char*)&sbuf[bq][3][0] + 4096 + woff);    \
    } while (0)

    float rv1[16], rv2[16]; int ri1[16];
#pragma unroll
    for (int e = 0; e < 16; ++e) { rv1[e] = 3e38f; rv2[e] = 3e38f; ri1[e] = 0; }

    f32x4 acc[4][4] = {};
    float e2v[4];
    int cbase = 0;

    STAGE(0, 0);
    __syncthreads();

    for (int ss = 0; ss < 64; ++ss) {
        const int cur = ss & 1;
        if (ss < 63) STAGE(cur ^ 1, ss + 1);  // prefetch overlaps compute

        if ((ss & 7) == 0) {                  // new nt: load e2 for epilogue
            const int nt = ng * 8 + (ss >> 3);
            cbase = nt * 128 + wc * 64 + l15;
#pragma unroll
            for (int ni = 0; ni < 4; ++ni) e2v[ni] = e2[cbase + ni * 16];
        }

        const u16* Ah = &sbuf[cur][0][0];
        const u16* Al = &sbuf[cur][1][0];
        const u16* Bh = &sbuf[cur][2][0];
        const u16* Bl = &sbuf[cur][3][0];

        bf16x8 ah[4], bh[4], xx[4];
#pragma unroll
        for (int i = 0; i < 4; ++i) ah[i] = FRAG(Ah, wr * 64 + i * 16 + l15);
#pragma unroll
        for (int i = 0; i < 4; ++i) bh[i] = FRAG(Bh, wc * 64 + i * 16 + l15);
#pragma unroll
        for (int i = 0; i < 4; ++i)
#pragma unroll
            for (int j = 0; j < 4; ++j)
                acc[i][j] = __builtin_amdgcn_mfma_f32_16x16x32_bf16(ah[i], bh[j], acc[i][j], 0, 0, 0);
#pragma unroll
        for (int i = 0; i < 4; ++i) xx[i] = FRAG(Bl, wc * 64 + i * 16 + l15);
#pragma unroll
        for (int i = 0; i < 4; ++i)
#pragma unroll
            for (int j = 0; j < 4; ++j)
                acc[i][j] = __builtin_amdgcn_mfma_f32_16x16x32_bf16(ah[i], xx[j], acc[i][j], 0, 0, 0);
#pragma unroll
        for (int i = 0; i < 4; ++i) xx[i] = FRAG(Al, wr * 64 + i * 16 + l15);
#pragma unroll
        for (int i = 0; i < 4; ++i)
#pragma unroll
            for (int j = 0; j < 4; ++j)
                acc[i][j] = __builtin_amdgcn_mfma_f32_16x16x32_bf16(xx[i], bh[j], acc[i][j], 0, 0, 0);

        if ((ss & 7) == 7) {                  // end of nt: push top-2, THEN reset acc
#pragma unroll
            for (int mi = 0; mi < 4; ++mi)
#pragma unroll
                for (int j = 0; j < 4; ++j) {
                    const int e = mi * 4 + j;
#pragma unroll
                    for (int ni = 0; ni < 4; ++ni) {
                        const float d = fmaf(-2.0f, acc[mi][ni][j], e2v[ni]);
                        top2_push(rv1[e], ri1[e], rv2[e], d, cbase + ni * 16);
                    }
                }
#pragma unroll
            for (int mi = 0; mi < 4; ++mi)
#pragma unroll
                for (int ni = 0; ni < 4; ++ni)
                    acc[mi][ni] = f32x4{0.f, 0.f, 0.f, 0.f};
        }
        __syncthreads();                      // drains vmcnt -> next buf ready, cur released
    }

    // single cross-lane merge per block
#pragma unroll
    for (int mi = 0; mi < 4; ++mi)
#pragma unroll
        for (int j = 0; j < 4; ++j) {
            const int e = mi * 4 + j;
            float v1 = rv1[e], v2 = rv2[e]; int i1 = ri1[e];
#pragma unroll
            for (int off = 1; off <= 8; off <<= 1) {
                const float ov1 = __shfl_xor(v1, off);
                const int   oi1 = __shfl_xor(i1, off);
                const float ov2 = __shfl_xor(v2, off);
                top2_merge(v1, i1, v2, ov1, oi1, ov2);
            }
            if (l15 == 0) {
                const int row = wr * 64 + mi * 16 + lq * 4 + j;
                lv1[row * 2 + wc] = v1; li1[row * 2 + wc] = i1; lv2[row * 2 + wc] = v2;
            }
        }
    __syncthreads();
    if (tid < 128) {
        float v1 = lv1[tid * 2], v2 = lv2[tid * 2]; int i1 = li1[tid * 2];
        top2_merge(v1, i1, v2, lv1[tid * 2 + 1], li1[tid * 2 + 1], lv2[tid * 2 + 1]);
        const size_t o = (size_t)ng * NPOS + (size_t)mt * 128 + tid;
        wv1[o] = v1; wi1[o] = i1; wv2[o] = v2;
    }
#undef FRAG
#undef STAGE
}

// ---------------------------------------------------------------------------
// merge_output: fold 8 panel top-2s per position, margin test -> rescue list,
// then gather z_q + straight-through write + loss partials.
// ---------------------------------------------------------------------------
__global__ __launch_bounds__(256)
void merge_output(const float* __restrict__ wv1, const int* __restrict__ wi1,
                  const float* __restrict__ wv2,
                  const float* __restrict__ z, const float* __restrict__ cb,
                  float* __restrict__ out, float* __restrict__ out_idxf,
                  float* __restrict__ partial, u32* __restrict__ presence,
                  int* __restrict__ rcnt, int* __restrict__ rlist,
                  int* __restrict__ ws_idx) {
    __shared__ int codes[64];
    __shared__ float red[256];
    const int tile = blockIdx.x;
    const int b    = tile >> 4;
    const int hw0  = (tile & 15) * 64;
    const int tid  = threadIdx.x;
    const int m    = tid & 63;
    const int cg   = tid >> 6;

    if (cg == 0) {
        const int pos = tile * 64 + m;
        float v1 = 3e38f, v2 = 3e38f; int i1 = 0;
#pragma unroll
        for (int g = 0; g < 8; ++g) {
            const size_t o = (size_t)g * NPOS + pos;
            top2_merge(v1, i1, v2, wv1[o], wi1[o], wv2[o]);
        }
        codes[m]      = i1;
        ws_idx[pos]   = i1;
        out_idxf[pos] = (float)i1;
        if (v2 - v1 < TAU) {
            const int s = atomicAdd(rcnt, 1);
            rlist[s] = pos;
        } else {
            atomicOr(&presence[b * 256 + (i1 >> 5)], 1u << (i1 & 31));
        }
    }
    __syncthreads();

    const int code = codes[m];
    const float* crow = cb  + (size_t)code * DIM;
    const float* zb   = z   + (size_t)b * ZSTRIDE + hw0 + m;
    float*       ob   = out + (size_t)b * ZSTRIDE + hw0 + m;

    float lsum = 0.0f;
#pragma unroll
    for (int q = 0; q < 16; ++q) {
        const int c = (cg * 16 + q) * 4;
        const float4 e = *(const float4*)(crow + c);
        const float z0 = zb[(size_t)(c + 0) * 1024];
        const float z1 = zb[(size_t)(c + 1) * 1024];
        const float z2 = zb[(size_t)(c + 2) * 1024];
        const float z3 = zb[(size_t)(c + 3) * 1024];
        const float d0 = e.x - z0, d1 = e.y - z1, d2 = e.z - z2, d3 = e.w - z3;
        lsum += d0 * d0 + d1 * d1 + d2 * d2 + d3 * d3;
        ob[(size_t)(c + 0) * 1024] = z0 + d0;
        ob[(size_t)(c + 1) * 1024] = z1 + d1;
        ob[(size_t)(c + 2) * 1024] = z2 + d2;
        ob[(size_t)(c + 3) * 1024] = z3 + d3;
    }
    red[tid] = lsum;
    __syncthreads();
    for (int o = 128; o > 0; o >>= 1) {
        if (tid < o) red[tid] += red[tid + o];
        __syncthreads();
    }
    if (tid == 0) partial[tile] = red[0];
}

// ---------------------------------------------------------------------------
// rescue_scan: grid-stride over n*32 chunk-jobs.  Block = (rescue entry e,
// chunk ch): 256 codes, ONE code per thread (4-acc dot, exact fp32), block
// argmin tree with ascending-index tie-break -> per-chunk best.
// ---------------------------------------------------------------------------
__global__ __launch_bounds__(256)
void rescue_scan(const float* __restrict__ z, const float* __restrict__ cb,
                 const float* __restrict__ e2, const int* __restrict__ rcnt,
                 const int* __restrict__ rlist,
                 float* __restrict__ rbv, int* __restrict__ rbi) {
    __shared__ float zvec[256];
    __shared__ float sv[256]; __shared__ int si[256];
    const int n = rcnt[0];
    const int t = threadIdx.x;
    for (int idx = blockIdx.x; idx < n * RCH; idx += gridDim.x) {
        const int e  = idx >> 5;              // RCH = 32
        const int ch = idx & 31;
        const int pos = rlist[e];
        const int b = pos >> 10, hw = pos & 1023;
        __syncthreads();                      // protect zvec from prev iter readers
        zvec[t] = z[(size_t)b * ZSTRIDE + (size_t)t * 1024 + hw];
        __syncthreads();

        const int c = ch * 256 + t;
        const float* cr = cb + (size_t)c * DIM;
        float a0 = 0.f, a1 = 0.f, a2 = 0.f, a3 = 0.f;
#pragma unroll
        for (int k = 0; k < DIM; k += 16) {
            const float4 v0 = *(const float4*)(cr + k);
            const float4 v1 = *(const float4*)(cr + k + 4);
            const float4 v2 = *(const float4*)(cr + k + 8);
            const float4 v3 = *(const float4*)(cr + k + 12);
            a0 = fmaf(zvec[k + 0], v0.x, a0); a0 = fmaf(zvec[k + 1], v0.y, a0);
            a0 = fmaf(zvec[k + 2], v0.z, a0); a0 = fmaf(zvec[k + 3], v0.w, a0);
            a1 = fmaf(zvec[k + 4], v1.x, a1); a1 = fmaf(zvec[k + 5], v1.y, a1);
            a1 = fmaf(zvec[k + 6], v1.z, a1); a1 = fmaf(zvec[k + 7], v1.w, a1);
            a2 = fmaf(zvec[k + 8], v2.x, a2); a2 = fmaf(zvec[k + 9], v2.y, a2);
            a2 = fmaf(zvec[k +10], v2.z, a2); a2 = fmaf(zvec[k +11], v2.w, a2);
            a3 = fmaf(zvec[k +12], v3.x, a3); a3 = fmaf(zvec[k +13], v3.y, a3);
            a3 = fmaf(zvec[k +14], v3.z, a3); a3 = fmaf(zvec[k +15], v3.w, a3);
        }
        const float dot = (a0 + a1) + (a2 + a3);
        sv[t] = fmaf(-2.f, dot, e2[c]); si[t] = c;
        __syncthreads();
        for (int o = 128; o > 0; o >>= 1) {
            if (t < o) {
                const float ov = sv[t + o]; const int oi = si[t + o];
                if (ov < sv[t] || (ov == sv[t] && oi < si[t])) { sv[t] = ov; si[t] = oi; }
            }
            __syncthreads();
        }
        if (t == 0) { rbv[e * RCH + ch] = sv[0]; rbi[e * RCH + ch] = si[0]; }
    }
}

// ---------------------------------------------------------------------------
// rescue_fix: one block per rescue entry; reduce 32 chunk-bests (ascending
// chunk order keeps lowest-index tie-break), patch idx/presence/z_q/ldel.
// ---------------------------------------------------------------------------
__global__ __launch_bounds__(256)
void rescue_fix(const float* __restrict__ z, const float* __restrict__ cb,
                const int* __restrict__ rcnt, const int* __restrict__ rlist,
                const float* __restrict__ rbv, const int* __restrict__ rbi,
                const int* __restrict__ ws_idx,
                float* __restrict__ out_idxf, u32* __restrict__ presence,
                float* __restrict__ out, float* __restrict__ ldel) {
    __shared__ int   bestc;
    __shared__ float red[4];
    const int n = rcnt[0];
    const int t = threadIdx.x;
    for (int e = blockIdx.x; e < n; e += gridDim.x) {
        const int pos = rlist[e];
        const int b = pos >> 10, hw = pos & 1023;
        if (t == 0) {
            float bv = 3e38f; int bi = 0x7fffffff;
            for (int ch = 0; ch < RCH; ++ch) {
                const float v = rbv[e * RCH + ch]; const int i = rbi[e * RCH + ch];
                if (v < bv || (v == bv && i < bi)) { bv = v; bi = i; }
            }
            bestc = bi;
            out_idxf[pos] = (float)bi;
            atomicOr(&presence[b * 256 + (bi >> 5)], 1u << (bi & 31));
        }
        __syncthreads();
        const int best = bestc;
        const int old  = ws_idx[pos];
        if (best != old) {
            const float zv = z[(size_t)b * ZSTRIDE + (size_t)t * 1024 + hw];
            const float en = cb[(size_t)best * DIM + t];
            const float eo = cb[(size_t)old  * DIM + t];
            const float dn = en - zv, dold = eo - zv;
            out[(size_t)b * ZSTRIDE + (size_t)t * 1024 + hw] = zv + dn;
            float dl = dn * dn - dold * dold;
#pragma unroll
            for (int o = 32; o > 0; o >>= 1) dl += __shfl_xor(dl, o);
            if ((t & 63) == 0) red[t >> 6] = dl;
            __syncthreads();
            if (t == 0) atomicAdd(ldel, red[0] + red[1] + red[2] + red[3]);
        }
        __syncthreads();
    }
}

// ---------------------------------------------------------------------------
__global__ __launch_bounds__(256)
void finalize_kernel(const float* __restrict__ partial,
                     const u32* __restrict__ presence,
                     const float* __restrict__ ldel,
                     float* __restrict__ out_loss, float* __restrict__ out_div) {
    __shared__ float sred[256];
    __shared__ int   ired[256];
    const int tid = threadIdx.x;
    float s = partial[tid];
    int cnt = 0;
    for (int w = tid; w < 16 * 256; w += 256) cnt += __popc(presence[w]);
    sred[tid] = s; ired[tid] = cnt;
    __syncthreads();
    for (int o = 128; o > 0; o >>= 1) {
        if (tid < o) { sred[tid] += sred[tid + o]; ired[tid] += ired[tid + o]; }
        __syncthreads();
    }
    if (tid == 0) {
        out_loss[0] = 1.25f * (sred[0] + ldel[0]) / (float)NELEM;
        out_div[0]  = (float)ired[0] / (float)NPOS;
    }
}

// ---------------------------------------------------------------------------
extern "C" void kernel_launch(void* const* d_in, const int* in_sizes, int n_in,
                              void* d_out, int out_size, void* d_ws, size_t ws_size,
                              hipStream_t stream) {
    const float* z  = (const float*)d_in[0];
    const float* cb = (const float*)d_in[1];
    float* out = (float*)d_out;
    char*  ws  = (char*)d_ws;

    u16*   Ahi = (u16*)(ws + WS_AHI);
    u16*   Alo = (u16*)(ws + WS_ALO);
    u16*   Bhi = (u16*)(ws + WS_BHI);
    u16*   Blo = (u16*)(ws + WS_BLO);
    float* e2  = (float*)(ws + WS_E2);
    float* wv1 = (float*)(ws + WS_WV1);
    int*   wi1 = (int*)(ws + WS_WI1);
    float* wv2 = (float*)(ws + WS_WV2);
    int*   ws_idx = (int*)(ws + WS_IDX);
    u32*   presence = (u32*)(ws + WS_PRES);
    int*   rcnt  = (int*)(ws + WS_RCNT);
    float* ldel  = (float*)(ws + WS_LDEL);
    int*   rlist = (int*)(ws + WS_RLIST);
    float* partial = (float*)(ws + WS_PART);
    float* rbv = (float*)(ws + WS_RBV);
    int*   rbi = (int*)(ws + WS_RBI);

    float* out_zq   = out;
    float* out_idxf = out + NELEM;
    float* out_loss = out + NELEM + NPOS;
    float* out_div  = out + NELEM + NPOS + 1;

    preprocess<<<3072, 256, 0, stream>>>(cb, z, Bhi, Blo, Ahi, Alo, e2, presence, rcnt, ldel);
    gemm_argmin<<<1024, 256, 0, stream>>>(Ahi, Alo, Bhi, Blo, e2, wv1, wi1, wv2);
    merge_output<<<NPOS / 64, 256, 0, stream>>>(wv1, wi1, wv2, z, cb, out_zq, out_idxf,
                                                partial, presence, rcnt, rlist, ws_idx);
    rescue_scan<<<2048, 256, 0, stream>>>(z, cb, e2, rcnt, rlist, rbv, rbi);
    rescue_fix<<<256, 256, 0, stream>>>(z, cb, rcnt, rlist, rbv, rbi, ws_idx,
                                        out_idxf, presence, out_zq, ldel);
    finalize_kernel<<<1, 256, 0, stream>>>(partial, presence, ldel, out_loss, out_div);
}